// Round 8
// baseline (411.839 us; speedup 1.0000x reference)
//
#include <hip/hip_runtime.h>
#include <hip/hip_bf16.h>
#include <cstdint>
#include <cstddef>

#define HID 1024
#define NH 16
#define DH 64
#define SEQ 2048
#define BATCH 2
#define BS (BATCH*SEQ)   // 4096
#define LOG2E 1.4426950408889634f
#define PADK 68          // LDS row stride in shorts (136B) — measured 0 conflicts

typedef __attribute__((ext_vector_type(8))) short bf16x8;
typedef __attribute__((ext_vector_type(4))) float f32x4;

static __device__ __forceinline__ float fast_exp2(float x) {
    return __builtin_amdgcn_exp2f(x);
}

// f32->bf16 RNE via the COMPILER's native path (round-5 verified).
// Hand-written v_cvt_pk asm miscompiles here (rounds 2/3) — do not use.
static __device__ __forceinline__ short f2bf(float f) {
    union { __hip_bfloat16 h; short s; } cv;
    cv.h = __float2bfloat16(f);
    return cv.s;
}
static __device__ __forceinline__ unsigned pack2(float a, float b) {
    union { __hip_bfloat162 h2; unsigned u; } cv;
    cv.h2 = __float22bfloat162_rn(make_float2(a, b));
    return cv.u;
}
static __device__ __forceinline__ float bfu(unsigned short v) {
    union { float f; unsigned u; } x; x.u = (unsigned)v << 16; return x.f;
}

// global -> LDS direct DMA, 16B per lane (global_load_lds_dwordx4).
typedef const __attribute__((address_space(1))) unsigned gas_u32;
typedef __attribute__((address_space(3))) unsigned las_u32;
static __device__ __forceinline__ void gload_lds16(const short* g, short* l) {
    __builtin_amdgcn_global_load_lds((gas_u32*)g, (las_u32*)l, 16, 0, 0);
}

// ---------------------------------------------------------------------------
// prep: Wqkv [1024][3072] fp32 -> wqkvT [3072][1024] bf16 (transpose+convert)
//       Wout [1024][1024] fp32 -> woutT [1024][1024] bf16
//       x    [4096][1024] fp32 -> xb    [4096][1024] bf16 (straight convert)
// ---------------------------------------------------------------------------
__global__ __launch_bounds__(256)
void prep(const float* __restrict__ Wqkv, const float* __restrict__ Wout,
          const float* __restrict__ x,
          short* __restrict__ wqkvT, short* __restrict__ woutT,
          short* __restrict__ xb)
{
    __shared__ short tl[64][66];
    const int bid = blockIdx.x;
    const int t = threadIdx.x;

    if (bid >= 1024) {
        const float4* x4 = (const float4*)x;
        uint2* xo = (uint2*)xb;
        const int base = (bid - 1024) * 4096 + t;
        #pragma unroll
        for (int i = 0; i < 16; ++i) {
            float4 f = x4[base + i*256];
            xo[base + i*256] = make_uint2(pack2(f.x, f.y), pack2(f.z, f.w));
        }
        return;
    }

    const float* W; short* WT; int Nw, K, k0, n0;
    if (bid < 768) {
        W = Wqkv; WT = wqkvT; Nw = 3072; K = 1024;
        n0 = (bid % 48) * 64; k0 = (bid / 48) * 64;
    } else {
        W = Wout; WT = woutT; Nw = 1024; K = 1024;
        int b2 = bid - 768;
        n0 = (b2 & 15) * 64; k0 = (b2 >> 4) * 64;
    }
    const int r = t >> 2, c0 = (t & 3) * 16;
    const float* src = W + (size_t)(k0 + r) * Nw + n0 + c0;
    #pragma unroll
    for (int i = 0; i < 16; i += 4) {
        float4 f = *(const float4*)(src + i);
        tl[r][c0+i+0] = f2bf(f.x); tl[r][c0+i+1] = f2bf(f.y);
        tl[r][c0+i+2] = f2bf(f.z); tl[r][c0+i+3] = f2bf(f.w);
    }
    __syncthreads();
    short* dst = WT + (size_t)(n0 + r) * K + k0 + c0;
    unsigned buf[8];
    #pragma unroll
    for (int i = 0; i < 8; ++i) {
        unsigned lo = (unsigned short)tl[c0 + 2*i    ][r];
        unsigned hi = (unsigned short)tl[c0 + 2*i + 1][r];
        buf[i] = lo | (hi << 16);
    }
    *(uint4*)dst       = *(uint4*)&buf[0];
    *((uint4*)dst + 1) = *(uint4*)&buf[4];
}

// ---------------------------------------------------------------------------
// m97-structure bf16 MFMA GEMM: C = A @ Bt^T. 128xBN tile, BK=64.
// ---------------------------------------------------------------------------
template<int CMODE, int BN>
__global__ __launch_bounds__(256, 3)
void gemm_lds(const short* __restrict__ A, const short* __restrict__ Bt,
              float* __restrict__ Cf,
              float* __restrict__ kc, float* __restrict__ vc,
              short* __restrict__ qb, short* __restrict__ kb, short* __restrict__ vt,
              int M, int N, int K)
{
    constexpr int WN = BN / 2;      // wave N span
    constexpr int NF = WN / 16;     // N fragments per wave
    __shared__ short As[128*64];
    __shared__ short Bs[BN*64];
    const int t    = threadIdx.x;
    const int wave = t >> 6, lane = t & 63;
    const int quad = lane >> 4, l16 = lane & 15;
    const int wrow = (wave & 1) * 64, wcol = (wave >> 1) * WN;
    const int n0 = blockIdx.x * BN, m0 = blockIdx.y * 128;

    f32x4 acc[4][NF];
    #pragma unroll
    for (int mi = 0; mi < 4; ++mi)
        #pragma unroll
        for (int nj = 0; nj < NF; ++nj) acc[mi][nj] = (f32x4){0.f,0.f,0.f,0.f};

    const int lr = lane >> 3;          // row within 8-row chunk
    const int lc = (lane & 7) * 8;     // col (shorts) within row
    const short* Ab = A  + (size_t)(m0 + wave*32       + lr) * K + lc;
    const short* Bb = Bt + (size_t)(n0 + wave*(BN/4)   + lr) * K + lc;
    short* AsW = As + (wave*32)      * 64;
    short* BsW = Bs + (wave*(BN/4))  * 64;

    for (int kt = 0; kt < K; kt += 64) {
        #pragma unroll
        for (int i = 0; i < 4; ++i)
            gload_lds16(Ab + (size_t)(i*8)*K + kt, AsW + i*512);
        #pragma unroll
        for (int i = 0; i < BN/32; ++i)
            gload_lds16(Bb + (size_t)(i*8)*K + kt, BsW + i*512);
        __syncthreads();

        #pragma unroll
        for (int ks = 0; ks < 2; ++ks) {
            bf16x8 af[4], bfr[NF];
            #pragma unroll
            for (int mi = 0; mi < 4; ++mi)
                af[mi] = *(const bf16x8*)&As[(wrow + mi*16 + l16)*64 + ks*32 + quad*8];
            #pragma unroll
            for (int nj = 0; nj < NF; ++nj)
                bfr[nj] = *(const bf16x8*)&Bs[(wcol + nj*16 + l16)*64 + ks*32 + quad*8];
            #pragma unroll
            for (int mi = 0; mi < 4; ++mi)
                #pragma unroll
                for (int nj = 0; nj < NF; ++nj)
                    acc[mi][nj] = __builtin_amdgcn_mfma_f32_16x16x32_bf16(
                        af[mi], bfr[nj], acc[mi][nj], 0, 0, 0);
        }
        __syncthreads();
    }

    const int region = (CMODE == 0) ? (n0 >> 10) : 0;
    #pragma unroll
    for (int mi = 0; mi < 4; ++mi) {
        int rbase = m0 + wrow + mi*16 + quad*4;
        #pragma unroll
        for (int nj = 0; nj < NF; ++nj) {
            int col = n0 + wcol + nj*16 + l16;
            if (CMODE == 1) {
                #pragma unroll
                for (int reg = 0; reg < 4; ++reg)
                    Cf[(size_t)(rbase + reg) * N + col] = acc[mi][nj][reg];
            } else {
                int c = col & 1023;
                if (region == 0) {
                    #pragma unroll
                    for (int reg = 0; reg < 4; ++reg)
                        qb[(size_t)(rbase + reg) * HID + c] = f2bf(acc[mi][nj][reg] * LOG2E);
                } else if (region == 1) {
                    #pragma unroll
                    for (int reg = 0; reg < 4; ++reg) {
                        float v = acc[mi][nj][reg];
                        kc[(size_t)(rbase + reg) * HID + c] = v;
                        if (kb) kb[(size_t)(rbase + reg) * HID + c] = f2bf(v);
                    }
                } else {
                    #pragma unroll
                    for (int reg = 0; reg < 4; ++reg)
                        vc[(size_t)(rbase + reg) * HID + c] = acc[mi][nj][reg];
                    if (vt) {
                        int b = rbase >> 11, s = rbase & 2047;
                        int h = c >> 6, d = c & 63;
                        unsigned u[2] = {pack2(acc[mi][nj][0], acc[mi][nj][1]),
                                         pack2(acc[mi][nj][2], acc[mi][nj][3])};
                        *(uint2*)&vt[((size_t)((b*16 + h)*64 + d)) * SEQ + s] = *(uint2*)u;
                    }
                }
            }
        }
    }
}

// ---------------------------------------------------------------------------
// Flash MFMA attention v8: R4-proven block structure (QBLK=64, KVBLK=64,
// 256 thr, 26.6KB LDS, 2-barrier loop, VGPR ~52) + 2-WAY KEY SPLIT to grow
// the grid 1024->2048 (occupancy was grid-capped at 4 blocks/CU = 50%).
// Unnormalized softmax is split-associative: blocks write partial O (bf16)
// + partial row-sums (f32); combine kernel normalizes. Fallback (KVB=false)
// keeps the old single-pass form.
// ---------------------------------------------------------------------------
template<bool KVB>
__global__ __launch_bounds__(256, 6)
void attn_kernel(const short* qb,
                 const short* __restrict__ kb, const short* __restrict__ vtg,
                 const float* __restrict__ kc, const float* __restrict__ vc,
                 const int*   __restrict__ mask,
                 short* attn_b,           // KVB=false: normalized out (aliases qb)
                 short* __restrict__ opart,   // KVB=true: [2][BS][HID] bf16 partials
                 float* __restrict__ lsp)     // KVB=true: [B*NH][2][SEQ] f32 partial sums
{
    __shared__ short Ks[64*PADK];
    __shared__ short Vs[64*PADK];   // [d][key]
    __shared__ short Ps[64*PADK];
    __shared__ float Mk[64];        // per-key mask bias (0 or -2e9)

    const int t    = threadIdx.x;
    const int wave = t >> 6, lane = t & 63;
    const int quad = lane >> 4, l16 = lane & 15;

    const int blk = blockIdx.x;
    const int qt  = blk & 31;
    int sp, h, b;
    if (KVB) { sp = (blk >> 5) & 1; h = (blk >> 6) & 15; b = blk >> 10; }
    else     { sp = 0;              h = (blk >> 5) & 15; b = blk >> 9;  }
    const int q0  = qt * 64;
    const int j00 = sp << 10;               // key-range start
    const int NT  = KVB ? 16 : 32;          // KV-tiles this block processes
    const float slope2 = exp2f(-0.5f * (float)(h + 1)) * LOG2E;
    const int* mb = mask + b * SEQ;

    const int r  = t >> 2;          // staging row 0..63
    const int c0 = (t & 3) * 16;    // staging col group

    const int qrow0 = q0 + 16*wave + quad*4;   // first q-row of this lane's regs

    // ---- Q fragments in registers (q pre-scaled by log2e) ----
    bf16x8 aq[2];
    #pragma unroll
    for (int ks = 0; ks < 2; ++ks)
        aq[ks] = *(const bf16x8*)(qb + ((size_t)(b*SEQ + q0 + 16*wave + l16)) * HID
                                     + h*DH + ks*32 + quad*8);

    float ls[4];
    f32x4 Oacc[4];
    #pragma unroll
    for (int i = 0; i < 4; ++i) {
        ls[i] = 0.f;
        Oacc[i] = (f32x4){0.f,0.f,0.f,0.f};
    }

    if (KVB) {
        // ---------------- pipelined path (bf16 kb / transposed vt) ----------
        uint4 kr0, kr1, vr0, vr1; float mval = 0.f;
        const short* kbase = kb  + ((size_t)(b*SEQ + j00 + r)) * HID + h*DH + c0;
        const short* vbase = vtg + ((size_t)((b*NH + h)*DH + r)) * SEQ + j00 + c0;

        kr0 = *(const uint4*)(kbase);
        kr1 = *(const uint4*)(kbase + 8);
        vr0 = *(const uint4*)(vbase);
        vr1 = *(const uint4*)(vbase + 8);
        mval = (mb[j00 + t & 63 ? j00 + (t & 63) : j00] == 0) ? -2.0e9f : 0.f; // placeholder, fixed below
        mval = (t < 64) ? ((mb[j00 + t] == 0) ? -2.0e9f : 0.f) : 0.f;

        for (int kt = 0; kt < NT; ++kt) {
            const int j0 = j00 + kt * 64;
            __syncthreads();   // prev-iter LDS reads complete

            *(uint4*)&Ks[r*PADK + c0]     = kr0;
            *(uint4*)&Ks[r*PADK + c0 + 8] = kr1;
            *(uint4*)&Vs[r*PADK + c0]     = vr0;
            *(uint4*)&Vs[r*PADK + c0 + 8] = vr1;
            if (t < 64) Mk[t] = mval;

            if (kt < NT - 1) {
                const short* kn = kbase + (size_t)((kt + 1) * 64) * HID;
                const short* vn = vbase + (kt + 1) * 64;
                kr0 = *(const uint4*)(kn);
                kr1 = *(const uint4*)(kn + 8);
                vr0 = *(const uint4*)(vn);
                vr1 = *(const uint4*)(vn + 8);
                if (t < 64) mval = (mb[j0 + 64 + t] == 0) ? -2.0e9f : 0.f;
            }
            __syncthreads();   // staging visible

            // ---- QK^T ----
            f32x4 S[4];
            #pragma unroll
            for (int nt = 0; nt < 4; ++nt) S[nt] = (f32x4){0.f,0.f,0.f,0.f};
            #pragma unroll
            for (int ks = 0; ks < 2; ++ks) {
                bf16x8 bk[4];
                #pragma unroll
                for (int nt = 0; nt < 4; ++nt)
                    bk[nt] = *(const bf16x8*)&Ks[(nt*16 + l16)*PADK + ks*32 + quad*8];
                __builtin_amdgcn_s_setprio(1);
                #pragma unroll
                for (int nt = 0; nt < 4; ++nt)
                    S[nt] = __builtin_amdgcn_mfma_f32_16x16x32_bf16(
                        aq[ks], bk[nt], S[nt], 0, 0, 0);
                __builtin_amdgcn_s_setprio(0);
            }

            // ---- bias + mask + unnormalized exp2, P -> LDS ----
            #pragma unroll
            for (int nt = 0; nt < 4; ++nt) {
                int j = j0 + nt*16 + l16;
                float mn  = Mk[nt*16 + l16];
                float fdb = (float)(j - qrow0);
                float p[4];
                #pragma unroll
                for (int reg = 0; reg < 4; ++reg) {
                    float d = fminf(fdb - (float)reg, 0.f);
                    p[reg] = fast_exp2(fmaf(slope2, d, S[nt][reg]) + mn);
                    ls[reg] += p[reg];
                }
                #pragma unroll
                for (int reg = 0; reg < 4; ++reg)
                    Ps[(16*wave + quad*4 + reg)*PADK + nt*16 + l16] = f2bf(p[reg]);
            }

            // ---- PV (unnormalized accumulate) ----
            #pragma unroll
            for (int ks = 0; ks < 2; ++ks) {
                bf16x8 ap = *(const bf16x8*)&Ps[(16*wave + l16)*PADK + ks*32 + quad*8];
                bf16x8 bv[4];
                #pragma unroll
                for (int nt = 0; nt < 4; ++nt)
                    bv[nt] = *(const bf16x8*)&Vs[(nt*16 + l16)*PADK + ks*32 + quad*8];
                __builtin_amdgcn_s_setprio(1);
                #pragma unroll
                for (int nt = 0; nt < 4; ++nt)
                    Oacc[nt] = __builtin_amdgcn_mfma_f32_16x16x32_bf16(
                        ap, bv[nt], Oacc[nt], 0, 0, 0);
                __builtin_amdgcn_s_setprio(0);
            }
        }

        // ---- epilogue: partial row-sums + unnormalized partial O ----
        float s4[4];
        #pragma unroll
        for (int reg = 0; reg < 4; ++reg) {
            float s0 = ls[reg];
            #pragma unroll
            for (int off = 1; off <= 8; off <<= 1) s0 += __shfl_xor(s0, off, 64);
            s4[reg] = s0;
        }
        if (l16 == 0) {
            float4 v = make_float4(s4[0], s4[1], s4[2], s4[3]);
            *(float4*)&lsp[(((size_t)(b*NH + h)) * 2 + sp) * SEQ + qrow0] = v;
        }
        short* po = opart + (size_t)sp * BS * HID + (size_t)b * SEQ * HID + h * DH;
        #pragma unroll
        for (int nt = 0; nt < 4; ++nt) {
            int dcol = nt*16 + l16;
            #pragma unroll
            for (int reg = 0; reg < 4; ++reg) {
                int row = q0 + 16*wave + quad*4 + reg;
                po[(size_t)row * HID + dcol] = f2bf(Oacc[nt][reg]);
            }
        }
    } else {
        // ---------------- fallback: fp32 kc/vc staging, single-pass --------
        for (int kt = 0; kt < 32; ++kt) {
            const int j0 = kt * 64;
            __syncthreads();
            {
                const float* src = kc + ((size_t)(b*SEQ + j0 + r)) * HID + h*DH + c0;
                #pragma unroll
                for (int i = 0; i < 16; i += 4) {
                    float4 f = *(const float4*)(src + i);
                    *(unsigned*)&Ks[r*PADK + c0 + i]     = pack2(f.x, f.y);
                    *(unsigned*)&Ks[r*PADK + c0 + i + 2] = pack2(f.z, f.w);
                }
                int kp = t & 31, db = t >> 5;
                const float* v0 = vc + ((size_t)(b*SEQ + j0 + 2*kp)) * HID + h*DH + db*8;
                const float* v1 = v0 + HID;
                float4 a0 = *(const float4*)v0, a1 = *(const float4*)(v0 + 4);
                float4 b0 = *(const float4*)v1, b1 = *(const float4*)(v1 + 4);
                float va[8]  = {a0.x,a0.y,a0.z,a0.w,a1.x,a1.y,a1.z,a1.w};
                float vb2[8] = {b0.x,b0.y,b0.z,b0.w,b1.x,b1.y,b1.z,b1.w};
                #pragma unroll
                for (int i = 0; i < 8; ++i)
                    *(unsigned*)&Vs[(db*8 + i)*PADK + 2*kp] = pack2(va[i], vb2[i]);
                if (t < 64) Mk[t] = (mb[j0 + t] == 0) ? -2.0e9f : 0.f;
            }
            __syncthreads();

            f32x4 S[4];
            #pragma unroll
            for (int nt = 0; nt < 4; ++nt) S[nt] = (f32x4){0.f,0.f,0.f,0.f};
            #pragma unroll
            for (int ks = 0; ks < 2; ++ks) {
                bf16x8 bk[4];
                #pragma unroll
                for (int nt = 0; nt < 4; ++nt)
                    bk[nt] = *(const bf16x8*)&Ks[(nt*16 + l16)*PADK + ks*32 + quad*8];
                #pragma unroll
                for (int nt = 0; nt < 4; ++nt)
                    S[nt] = __builtin_amdgcn_mfma_f32_16x16x32_bf16(
                        aq[ks], bk[nt], S[nt], 0, 0, 0);
            }

            #pragma unroll
            for (int nt = 0; nt < 4; ++nt) {
                int j = j0 + nt*16 + l16;
                float mn  = Mk[nt*16 + l16];
                float fdb = (float)(j - qrow0);
                float p[4];
                #pragma unroll
                for (int reg = 0; reg < 4; ++reg) {
                    float d = fminf(fdb - (float)reg, 0.f);
                    p[reg] = fast_exp2(fmaf(slope2, d, S[nt][reg]) + mn);
                    ls[reg] += p[reg];
                }
                #pragma unroll
                for (int reg = 0; reg < 4; ++reg)
                    Ps[(16*wave + quad*4 + reg)*PADK + nt*16 + l16] = f2bf(p[reg]);
            }

            #pragma unroll
            for (int ks = 0; ks < 2; ++ks) {
                bf16x8 ap = *(const bf16x8*)&Ps[(16*wave + l16)*PADK + ks*32 + quad*8];
                bf16x8 bv[4];
                #pragma unroll
                for (int nt = 0; nt < 4; ++nt)
                    bv[nt] = *(const bf16x8*)&Vs[(nt*16 + l16)*PADK + ks*32 + quad*8];
                #pragma unroll
                for (int nt = 0; nt < 4; ++nt)
                    Oacc[nt] = __builtin_amdgcn_mfma_f32_16x16x32_bf16(
                        ap, bv[nt], Oacc[nt], 0, 0, 0);
            }
        }

        float rinv[4];
        #pragma unroll
        for (int reg = 0; reg < 4; ++reg) {
            float s0 = ls[reg];
            #pragma unroll
            for (int off = 1; off <= 8; off <<= 1) s0 += __shfl_xor(s0, off, 64);
            rinv[reg] = 1.0f / s0;
        }
        short* ap = attn_b + (size_t)b * SEQ * HID + h * DH;
        #pragma unroll
        for (int nt = 0; nt < 4; ++nt) {
            int dcol = nt*16 + l16;
            #pragma unroll
            for (int reg = 0; reg < 4; ++reg) {
                int row = q0 + 16*wave + quad*4 + reg;
                ap[(size_t)row * HID + dcol] = f2bf(Oacc[nt][reg] * rinv[reg]);
            }
        }
    }
}

// ---------------------------------------------------------------------------
// combine: qb[row][col] = (O0 + O1) / (l0 + l1), bf16 out.
// op: [2][BS][HID] bf16, lsp: [B*NH][2][SEQ] f32. One uint4 (8 bf16) / thread.
// ---------------------------------------------------------------------------
__global__ __launch_bounds__(256)
void combine(const short* __restrict__ op, const float* __restrict__ lsp,
             short* __restrict__ qb)
{
    const int i = blockIdx.x * 256 + threadIdx.x;    // 0 .. BS*HID/8-1
    const size_t off = (size_t)i * 8;
    const int row = (int)(off >> 10);
    const int col = (int)(off & 1023);
    const int b = row >> 11, s = row & 2047, h = col >> 6;
    const float* lb = lsp + ((size_t)(b*NH + h)) * 2 * SEQ;
    const float inv = 1.0f / (lb[s] + lb[SEQ + s]);
    uint4 a = *(const uint4*)(op + off);
    uint4 c = *(const uint4*)(op + (size_t)BS * HID + off);
    unsigned ua[4] = {a.x, a.y, a.z, a.w};
    unsigned uc[4] = {c.x, c.y, c.z, c.w};
    unsigned uo[4];
    #pragma unroll
    for (int k = 0; k < 4; ++k) {
        float a0 = bfu((unsigned short)(ua[k] & 0xFFFF));
        float a1 = bfu((unsigned short)(ua[k] >> 16));
        float c0 = bfu((unsigned short)(uc[k] & 0xFFFF));
        float c1 = bfu((unsigned short)(uc[k] >> 16));
        uo[k] = pack2((a0 + c0) * inv, (a1 + c1) * inv);
    }
    *(uint4*)(qb + off) = *(uint4*)uo;
}

// ---------------------------------------------------------------------------
extern "C" void kernel_launch(void* const* d_in, const int* in_sizes, int n_in,
                              void* d_out, int out_size, void* d_ws, size_t ws_size,
                              hipStream_t stream)
{
    const float* x    = (const float*)d_in[0];
    const int*   mask = (const int*)  d_in[1];
    const float* Wqkv = (const float*)d_in[2];
    const float* Wout = (const float*)d_in[3];

    float* out = (float*)d_out;
    float* kc  = out + (size_t)BS * HID;
    float* vc  = kc  + (size_t)BS * HID;

    char*  ws    = (char*)d_ws;
    short* qb    = (short*)ws;                          // 8 MB  [BS][HID] bf16
    short* wqkvT = (short*)(ws + (8u << 20));           // 6 MB (dead after gemm1)
    short* woutT = (short*)(ws + (14u << 20));          // 2 MB
    const bool full = ws_size >= (32u << 20);
    short* kb = full ? (short*)(ws + (16u << 20)) : nullptr;  // 8 MB [BS][HID] bf16
    short* vt = full ? (short*)(ws + (24u << 20)) : nullptr;  // 8 MB [B][H][64][SEQ] bf16

    // xb (bf16 x, 8 MB) + attn partials (16 MB) live in the `out` region of
    // d_out — xb is consumed by gemm1 before attn writes partials there.
    short* xb    = (short*)out;
    short* opart = (short*)out;                 // [2][BS][HID] bf16 = 16 MB
    float* lsp   = (float*)wqkvT;               // 512 KB in dead wqkvT region

    prep<<<dim3(1280), dim3(256), 0, stream>>>(Wqkv, Wout, x, wqkvT, woutT, xb);

    gemm_lds<0,128><<<dim3(24, 32), dim3(256), 0, stream>>>(
        xb, wqkvT, nullptr, kc, vc, qb, kb, vt, BS, 3*HID, HID);

    if (full) {
        attn_kernel<true><<<dim3(2048), dim3(256), 0, stream>>>(
            qb, kb, vt, kc, vc, mask, qb, opart, lsp);
        combine<<<dim3(BS*HID/8/256), dim3(256), 0, stream>>>(opart, lsp, qb);
    } else {
        attn_kernel<false><<<dim3(1024), dim3(256), 0, stream>>>(
            qb, nullptr, nullptr, kc, vc, mask, qb, nullptr, nullptr);
    }

    gemm_lds<1,64><<<dim3(16, 32), dim3(256), 0, stream>>>(
        qb, woutT, out, nullptr, nullptr, nullptr, nullptr, nullptr, BS, HID, HID);
}

// Round 9
// 232.888 us; speedup vs baseline: 1.7684x; 1.7684x over previous
//
#include <hip/hip_runtime.h>
#include <hip/hip_bf16.h>
#include <cstdint>
#include <cstddef>

#define HID 1024
#define NH 16
#define DH 64
#define SEQ 2048
#define BATCH 2
#define BS (BATCH*SEQ)   // 4096
#define LOG2E 1.4426950408889634f
#define PADK 68          // LDS row stride in shorts (136B) — measured 0 conflicts

typedef __attribute__((ext_vector_type(8))) short bf16x8;
typedef __attribute__((ext_vector_type(4))) float f32x4;

static __device__ __forceinline__ float fast_exp2(float x) {
    return __builtin_amdgcn_exp2f(x);
}

// f32->bf16 RNE via the COMPILER's native path (round-5 verified).
// Hand-written v_cvt_pk asm miscompiles here (rounds 2/3) — do not use.
static __device__ __forceinline__ short f2bf(float f) {
    union { __hip_bfloat16 h; short s; } cv;
    cv.h = __float2bfloat16(f);
    return cv.s;
}
static __device__ __forceinline__ unsigned pack2(float a, float b) {
    union { __hip_bfloat162 h2; unsigned u; } cv;
    cv.h2 = __float22bfloat162_rn(make_float2(a, b));
    return cv.u;
}
static __device__ __forceinline__ float bfu(unsigned short v) {
    union { float f; unsigned u; } x; x.u = (unsigned)v << 16; return x.f;
}

// global -> LDS direct DMA, 16B per lane (global_load_lds_dwordx4).
typedef const __attribute__((address_space(1))) unsigned gas_u32;
typedef __attribute__((address_space(3))) unsigned las_u32;
static __device__ __forceinline__ void gload_lds16(const short* g, short* l) {
    __builtin_amdgcn_global_load_lds((gas_u32*)g, (las_u32*)l, 16, 0, 0);
}

// ---------------------------------------------------------------------------
// prep: Wqkv [1024][3072] fp32 -> wqkvT [3072][1024] bf16 (transpose+convert)
//       Wout [1024][1024] fp32 -> woutT [1024][1024] bf16
//       x    [4096][1024] fp32 -> xb    [4096][1024] bf16 (straight convert)
// ---------------------------------------------------------------------------
__global__ __launch_bounds__(256)
void prep(const float* __restrict__ Wqkv, const float* __restrict__ Wout,
          const float* __restrict__ x,
          short* __restrict__ wqkvT, short* __restrict__ woutT,
          short* __restrict__ xb)
{
    __shared__ short tl[64][66];
    const int bid = blockIdx.x;
    const int t = threadIdx.x;

    if (bid >= 1024) {
        const float4* x4 = (const float4*)x;
        uint2* xo = (uint2*)xb;
        const int base = (bid - 1024) * 4096 + t;
        #pragma unroll
        for (int i = 0; i < 16; ++i) {
            float4 f = x4[base + i*256];
            xo[base + i*256] = make_uint2(pack2(f.x, f.y), pack2(f.z, f.w));
        }
        return;
    }

    const float* W; short* WT; int Nw, K, k0, n0;
    if (bid < 768) {
        W = Wqkv; WT = wqkvT; Nw = 3072; K = 1024;
        n0 = (bid % 48) * 64; k0 = (bid / 48) * 64;
    } else {
        W = Wout; WT = woutT; Nw = 1024; K = 1024;
        int b2 = bid - 768;
        n0 = (b2 & 15) * 64; k0 = (b2 >> 4) * 64;
    }
    const int r = t >> 2, c0 = (t & 3) * 16;
    const float* src = W + (size_t)(k0 + r) * Nw + n0 + c0;
    #pragma unroll
    for (int i = 0; i < 16; i += 4) {
        float4 f = *(const float4*)(src + i);
        tl[r][c0+i+0] = f2bf(f.x); tl[r][c0+i+1] = f2bf(f.y);
        tl[r][c0+i+2] = f2bf(f.z); tl[r][c0+i+3] = f2bf(f.w);
    }
    __syncthreads();
    short* dst = WT + (size_t)(n0 + r) * K + k0 + c0;
    unsigned buf[8];
    #pragma unroll
    for (int i = 0; i < 8; ++i) {
        unsigned lo = (unsigned short)tl[c0 + 2*i    ][r];
        unsigned hi = (unsigned short)tl[c0 + 2*i + 1][r];
        buf[i] = lo | (hi << 16);
    }
    *(uint4*)dst       = *(uint4*)&buf[0];
    *((uint4*)dst + 1) = *(uint4*)&buf[4];
}

// ---------------------------------------------------------------------------
// m97-structure bf16 MFMA GEMM: C = A @ Bt^T. 128xBN tile, BK=64.
// ---------------------------------------------------------------------------
template<int CMODE, int BN>
__global__ __launch_bounds__(256, 3)
void gemm_lds(const short* __restrict__ A, const short* __restrict__ Bt,
              float* __restrict__ Cf,
              float* __restrict__ kc, float* __restrict__ vc,
              short* __restrict__ qb, short* __restrict__ kb, short* __restrict__ vt,
              int M, int N, int K)
{
    constexpr int WN = BN / 2;      // wave N span
    constexpr int NF = WN / 16;     // N fragments per wave
    __shared__ short As[128*64];
    __shared__ short Bs[BN*64];
    const int t    = threadIdx.x;
    const int wave = t >> 6, lane = t & 63;
    const int quad = lane >> 4, l16 = lane & 15;
    const int wrow = (wave & 1) * 64, wcol = (wave >> 1) * WN;
    const int n0 = blockIdx.x * BN, m0 = blockIdx.y * 128;

    f32x4 acc[4][NF];
    #pragma unroll
    for (int mi = 0; mi < 4; ++mi)
        #pragma unroll
        for (int nj = 0; nj < NF; ++nj) acc[mi][nj] = (f32x4){0.f,0.f,0.f,0.f};

    const int lr = lane >> 3;          // row within 8-row chunk
    const int lc = (lane & 7) * 8;     // col (shorts) within row
    const short* Ab = A  + (size_t)(m0 + wave*32       + lr) * K + lc;
    const short* Bb = Bt + (size_t)(n0 + wave*(BN/4)   + lr) * K + lc;
    short* AsW = As + (wave*32)      * 64;
    short* BsW = Bs + (wave*(BN/4))  * 64;

    for (int kt = 0; kt < K; kt += 64) {
        #pragma unroll
        for (int i = 0; i < 4; ++i)
            gload_lds16(Ab + (size_t)(i*8)*K + kt, AsW + i*512);
        #pragma unroll
        for (int i = 0; i < BN/32; ++i)
            gload_lds16(Bb + (size_t)(i*8)*K + kt, BsW + i*512);
        __syncthreads();

        #pragma unroll
        for (int ks = 0; ks < 2; ++ks) {
            bf16x8 af[4], bfr[NF];
            #pragma unroll
            for (int mi = 0; mi < 4; ++mi)
                af[mi] = *(const bf16x8*)&As[(wrow + mi*16 + l16)*64 + ks*32 + quad*8];
            #pragma unroll
            for (int nj = 0; nj < NF; ++nj)
                bfr[nj] = *(const bf16x8*)&Bs[(wcol + nj*16 + l16)*64 + ks*32 + quad*8];
            #pragma unroll
            for (int mi = 0; mi < 4; ++mi)
                #pragma unroll
                for (int nj = 0; nj < NF; ++nj)
                    acc[mi][nj] = __builtin_amdgcn_mfma_f32_16x16x32_bf16(
                        af[mi], bfr[nj], acc[mi][nj], 0, 0, 0);
        }
        __syncthreads();
    }

    const int region = (CMODE == 0) ? (n0 >> 10) : 0;
    #pragma unroll
    for (int mi = 0; mi < 4; ++mi) {
        int rbase = m0 + wrow + mi*16 + quad*4;
        #pragma unroll
        for (int nj = 0; nj < NF; ++nj) {
            int col = n0 + wcol + nj*16 + l16;
            if (CMODE == 1) {
                #pragma unroll
                for (int reg = 0; reg < 4; ++reg)
                    Cf[(size_t)(rbase + reg) * N + col] = acc[mi][nj][reg];
            } else {
                int c = col & 1023;
                if (region == 0) {
                    #pragma unroll
                    for (int reg = 0; reg < 4; ++reg)
                        qb[(size_t)(rbase + reg) * HID + c] = f2bf(acc[mi][nj][reg] * LOG2E);
                } else if (region == 1) {
                    #pragma unroll
                    for (int reg = 0; reg < 4; ++reg) {
                        float v = acc[mi][nj][reg];
                        kc[(size_t)(rbase + reg) * HID + c] = v;
                        if (kb) kb[(size_t)(rbase + reg) * HID + c] = f2bf(v);
                    }
                } else {
                    #pragma unroll
                    for (int reg = 0; reg < 4; ++reg)
                        vc[(size_t)(rbase + reg) * HID + c] = acc[mi][nj][reg];
                    if (vt) {
                        int b = rbase >> 11, s = rbase & 2047;
                        int h = c >> 6, d = c & 63;
                        unsigned u[2] = {pack2(acc[mi][nj][0], acc[mi][nj][1]),
                                         pack2(acc[mi][nj][2], acc[mi][nj][3])};
                        *(uint2*)&vt[((size_t)((b*16 + h)*64 + d)) * SEQ + s] = *(uint2*)u;
                    }
                }
            }
        }
    }
}

// ---------------------------------------------------------------------------
// Flash MFMA attention v8b: R4 block structure (QBLK=64, KVBLK=64, 256 thr,
// 26.6KB LDS, 2-barrier loop) + 2-way key split (grid 2048). launch_bounds
// REVERTED to (256,4): R8's (256,6) forced VGPR 40 -> 532MB scratch spill.
// (256,4) compiles to 52 VGPR (<=64 => HW can still run 6 blocks/CU; the
// declared minimum does not cap actual occupancy).
// ---------------------------------------------------------------------------
template<bool KVB>
__global__ __launch_bounds__(256, 4)
void attn_kernel(const short* qb,
                 const short* __restrict__ kb, const short* __restrict__ vtg,
                 const float* __restrict__ kc, const float* __restrict__ vc,
                 const int*   __restrict__ mask,
                 short* attn_b,           // KVB=false: normalized out (aliases qb)
                 short* __restrict__ opart,   // KVB=true: [2][BS][HID] bf16 partials
                 float* __restrict__ lsp)     // KVB=true: [B*NH][2][SEQ] f32 partial sums
{
    __shared__ short Ks[64*PADK];
    __shared__ short Vs[64*PADK];   // [d][key]
    __shared__ short Ps[64*PADK];
    __shared__ float Mk[64];        // per-key mask bias (0 or -2e9)

    const int t    = threadIdx.x;
    const int wave = t >> 6, lane = t & 63;
    const int quad = lane >> 4, l16 = lane & 15;

    const int blk = blockIdx.x;
    const int qt  = blk & 31;
    int sp, h, b;
    if (KVB) { sp = (blk >> 5) & 1; h = (blk >> 6) & 15; b = blk >> 10; }
    else     { sp = 0;              h = (blk >> 5) & 15; b = blk >> 9;  }
    const int q0  = qt * 64;
    const int j00 = sp << 10;               // key-range start
    const int NT  = KVB ? 16 : 32;          // KV-tiles this block processes
    const float slope2 = exp2f(-0.5f * (float)(h + 1)) * LOG2E;
    const int* mb = mask + b * SEQ;

    const int r  = t >> 2;          // staging row 0..63
    const int c0 = (t & 3) * 16;    // staging col group

    const int qrow0 = q0 + 16*wave + quad*4;   // first q-row of this lane's regs

    // ---- Q fragments in registers (q pre-scaled by log2e) ----
    bf16x8 aq[2];
    #pragma unroll
    for (int ks = 0; ks < 2; ++ks)
        aq[ks] = *(const bf16x8*)(qb + ((size_t)(b*SEQ + q0 + 16*wave + l16)) * HID
                                     + h*DH + ks*32 + quad*8);

    float ls[4];
    f32x4 Oacc[4];
    #pragma unroll
    for (int i = 0; i < 4; ++i) {
        ls[i] = 0.f;
        Oacc[i] = (f32x4){0.f,0.f,0.f,0.f};
    }

    if (KVB) {
        // ---------------- pipelined path (bf16 kb / transposed vt) ----------
        uint4 kr0, kr1, vr0, vr1; float mval = 0.f;
        const short* kbase = kb  + ((size_t)(b*SEQ + j00 + r)) * HID + h*DH + c0;
        const short* vbase = vtg + ((size_t)((b*NH + h)*DH + r)) * SEQ + j00 + c0;

        kr0 = *(const uint4*)(kbase);
        kr1 = *(const uint4*)(kbase + 8);
        vr0 = *(const uint4*)(vbase);
        vr1 = *(const uint4*)(vbase + 8);
        if (t < 64) mval = (mb[j00 + t] == 0) ? -2.0e9f : 0.f;

        for (int kt = 0; kt < NT; ++kt) {
            const int j0 = j00 + kt * 64;
            __syncthreads();   // prev-iter LDS reads complete

            *(uint4*)&Ks[r*PADK + c0]     = kr0;
            *(uint4*)&Ks[r*PADK + c0 + 8] = kr1;
            *(uint4*)&Vs[r*PADK + c0]     = vr0;
            *(uint4*)&Vs[r*PADK + c0 + 8] = vr1;
            if (t < 64) Mk[t] = mval;

            if (kt < NT - 1) {
                const short* kn = kbase + (size_t)((kt + 1) * 64) * HID;
                const short* vn = vbase + (kt + 1) * 64;
                kr0 = *(const uint4*)(kn);
                kr1 = *(const uint4*)(kn + 8);
                vr0 = *(const uint4*)(vn);
                vr1 = *(const uint4*)(vn + 8);
                if (t < 64) mval = (mb[j0 + 64 + t] == 0) ? -2.0e9f : 0.f;
            }
            __syncthreads();   // staging visible

            // ---- QK^T ----
            f32x4 S[4];
            #pragma unroll
            for (int nt = 0; nt < 4; ++nt) S[nt] = (f32x4){0.f,0.f,0.f,0.f};
            #pragma unroll
            for (int ks = 0; ks < 2; ++ks) {
                bf16x8 bk[4];
                #pragma unroll
                for (int nt = 0; nt < 4; ++nt)
                    bk[nt] = *(const bf16x8*)&Ks[(nt*16 + l16)*PADK + ks*32 + quad*8];
                __builtin_amdgcn_s_setprio(1);
                #pragma unroll
                for (int nt = 0; nt < 4; ++nt)
                    S[nt] = __builtin_amdgcn_mfma_f32_16x16x32_bf16(
                        aq[ks], bk[nt], S[nt], 0, 0, 0);
                __builtin_amdgcn_s_setprio(0);
            }

            // ---- bias + mask + unnormalized exp2, P -> LDS ----
            #pragma unroll
            for (int nt = 0; nt < 4; ++nt) {
                int j = j0 + nt*16 + l16;
                float mn  = Mk[nt*16 + l16];
                float fdb = (float)(j - qrow0);
                float p[4];
                #pragma unroll
                for (int reg = 0; reg < 4; ++reg) {
                    float d = fminf(fdb - (float)reg, 0.f);
                    p[reg] = fast_exp2(fmaf(slope2, d, S[nt][reg]) + mn);
                    ls[reg] += p[reg];
                }
                #pragma unroll
                for (int reg = 0; reg < 4; ++reg)
                    Ps[(16*wave + quad*4 + reg)*PADK + nt*16 + l16] = f2bf(p[reg]);
            }

            // ---- PV (unnormalized accumulate) ----
            #pragma unroll
            for (int ks = 0; ks < 2; ++ks) {
                bf16x8 ap = *(const bf16x8*)&Ps[(16*wave + l16)*PADK + ks*32 + quad*8];
                bf16x8 bv[4];
                #pragma unroll
                for (int nt = 0; nt < 4; ++nt)
                    bv[nt] = *(const bf16x8*)&Vs[(nt*16 + l16)*PADK + ks*32 + quad*8];
                __builtin_amdgcn_s_setprio(1);
                #pragma unroll
                for (int nt = 0; nt < 4; ++nt)
                    Oacc[nt] = __builtin_amdgcn_mfma_f32_16x16x32_bf16(
                        ap, bv[nt], Oacc[nt], 0, 0, 0);
                __builtin_amdgcn_s_setprio(0);
            }
        }

        // ---- epilogue: partial row-sums + unnormalized partial O ----
        float s4[4];
        #pragma unroll
        for (int reg = 0; reg < 4; ++reg) {
            float s0 = ls[reg];
            #pragma unroll
            for (int off = 1; off <= 8; off <<= 1) s0 += __shfl_xor(s0, off, 64);
            s4[reg] = s0;
        }
        if (l16 == 0) {
            float4 v = make_float4(s4[0], s4[1], s4[2], s4[3]);
            *(float4*)&lsp[(((size_t)(b*NH + h)) * 2 + sp) * SEQ + qrow0] = v;
        }
        short* po = opart + (size_t)sp * BS * HID + (size_t)b * SEQ * HID + h * DH;
        #pragma unroll
        for (int nt = 0; nt < 4; ++nt) {
            int dcol = nt*16 + l16;
            #pragma unroll
            for (int reg = 0; reg < 4; ++reg) {
                int row = q0 + 16*wave + quad*4 + reg;
                po[(size_t)row * HID + dcol] = f2bf(Oacc[nt][reg]);
            }
        }
    } else {
        // ---------------- fallback: fp32 kc/vc staging, single-pass --------
        for (int kt = 0; kt < 32; ++kt) {
            const int j0 = kt * 64;
            __syncthreads();
            {
                const float* src = kc + ((size_t)(b*SEQ + j0 + r)) * HID + h*DH + c0;
                #pragma unroll
                for (int i = 0; i < 16; i += 4) {
                    float4 f = *(const float4*)(src + i);
                    *(unsigned*)&Ks[r*PADK + c0 + i]     = pack2(f.x, f.y);
                    *(unsigned*)&Ks[r*PADK + c0 + i + 2] = pack2(f.z, f.w);
                }
                int kp = t & 31, db = t >> 5;
                const float* v0 = vc + ((size_t)(b*SEQ + j0 + 2*kp)) * HID + h*DH + db*8;
                const float* v1 = v0 + HID;
                float4 a0 = *(const float4*)v0, a1 = *(const float4*)(v0 + 4);
                float4 b0 = *(const float4*)v1, b1 = *(const float4*)(v1 + 4);
                float va[8]  = {a0.x,a0.y,a0.z,a0.w,a1.x,a1.y,a1.z,a1.w};
                float vb2[8] = {b0.x,b0.y,b0.z,b0.w,b1.x,b1.y,b1.z,b1.w};
                #pragma unroll
                for (int i = 0; i < 8; ++i)
                    *(unsigned*)&Vs[(db*8 + i)*PADK + 2*kp] = pack2(va[i], vb2[i]);
                if (t < 64) Mk[t] = (mb[j0 + t] == 0) ? -2.0e9f : 0.f;
            }
            __syncthreads();

            f32x4 S[4];
            #pragma unroll
            for (int nt = 0; nt < 4; ++nt) S[nt] = (f32x4){0.f,0.f,0.f,0.f};
            #pragma unroll
            for (int ks = 0; ks < 2; ++ks) {
                bf16x8 bk[4];
                #pragma unroll
                for (int nt = 0; nt < 4; ++nt)
                    bk[nt] = *(const bf16x8*)&Ks[(nt*16 + l16)*PADK + ks*32 + quad*8];
                #pragma unroll
                for (int nt = 0; nt < 4; ++nt)
                    S[nt] = __builtin_amdgcn_mfma_f32_16x16x32_bf16(
                        aq[ks], bk[nt], S[nt], 0, 0, 0);
            }

            #pragma unroll
            for (int nt = 0; nt < 4; ++nt) {
                int j = j0 + nt*16 + l16;
                float mn  = Mk[nt*16 + l16];
                float fdb = (float)(j - qrow0);
                float p[4];
                #pragma unroll
                for (int reg = 0; reg < 4; ++reg) {
                    float d = fminf(fdb - (float)reg, 0.f);
                    p[reg] = fast_exp2(fmaf(slope2, d, S[nt][reg]) + mn);
                    ls[reg] += p[reg];
                }
                #pragma unroll
                for (int reg = 0; reg < 4; ++reg)
                    Ps[(16*wave + quad*4 + reg)*PADK + nt*16 + l16] = f2bf(p[reg]);
            }

            #pragma unroll
            for (int ks = 0; ks < 2; ++ks) {
                bf16x8 ap = *(const bf16x8*)&Ps[(16*wave + l16)*PADK + ks*32 + quad*8];
                bf16x8 bv[4];
                #pragma unroll
                for (int nt = 0; nt < 4; ++nt)
                    bv[nt] = *(const bf16x8*)&Vs[(nt*16 + l16)*PADK + ks*32 + quad*8];
                #pragma unroll
                for (int nt = 0; nt < 4; ++nt)
                    Oacc[nt] = __builtin_amdgcn_mfma_f32_16x16x32_bf16(
                        ap, bv[nt], Oacc[nt], 0, 0, 0);
            }
        }

        float rinv[4];
        #pragma unroll
        for (int reg = 0; reg < 4; ++reg) {
            float s0 = ls[reg];
            #pragma unroll
            for (int off = 1; off <= 8; off <<= 1) s0 += __shfl_xor(s0, off, 64);
            rinv[reg] = 1.0f / s0;
        }
        short* ap = attn_b + (size_t)b * SEQ * HID + h * DH;
        #pragma unroll
        for (int nt = 0; nt < 4; ++nt) {
            int dcol = nt*16 + l16;
            #pragma unroll
            for (int reg = 0; reg < 4; ++reg) {
                int row = q0 + 16*wave + quad*4 + reg;
                ap[(size_t)row * HID + dcol] = f2bf(Oacc[nt][reg] * rinv[reg]);
            }
        }
    }
}

// ---------------------------------------------------------------------------
// combine: qb[row][col] = (O0 + O1) / (l0 + l1), bf16 out.
// op: [2][BS][HID] bf16, lsp: [B*NH][2][SEQ] f32. One uint4 (8 bf16) / thread.
// ---------------------------------------------------------------------------
__global__ __launch_bounds__(256)
void combine(const short* __restrict__ op, const float* __restrict__ lsp,
             short* __restrict__ qb)
{
    const int i = blockIdx.x * 256 + threadIdx.x;    // 0 .. BS*HID/8-1
    const size_t off = (size_t)i * 8;
    const int row = (int)(off >> 10);
    const int col = (int)(off & 1023);
    const int b = row >> 11, s = row & 2047, h = col >> 6;
    const float* lb = lsp + ((size_t)(b*NH + h)) * 2 * SEQ;
    const float inv = 1.0f / (lb[s] + lb[SEQ + s]);
    uint4 a = *(const uint4*)(op + off);
    uint4 c = *(const uint4*)(op + (size_t)BS * HID + off);
    unsigned ua[4] = {a.x, a.y, a.z, a.w};
    unsigned uc[4] = {c.x, c.y, c.z, c.w};
    unsigned uo[4];
    #pragma unroll
    for (int k = 0; k < 4; ++k) {
        float a0 = bfu((unsigned short)(ua[k] & 0xFFFF));
        float a1 = bfu((unsigned short)(ua[k] >> 16));
        float c0 = bfu((unsigned short)(uc[k] & 0xFFFF));
        float c1 = bfu((unsigned short)(uc[k] >> 16));
        uo[k] = pack2((a0 + c0) * inv, (a1 + c1) * inv);
    }
    *(uint4*)(qb + off) = *(uint4*)uo;
}

// ---------------------------------------------------------------------------
extern "C" void kernel_launch(void* const* d_in, const int* in_sizes, int n_in,
                              void* d_out, int out_size, void* d_ws, size_t ws_size,
                              hipStream_t stream)
{
    const float* x    = (const float*)d_in[0];
    const int*   mask = (const int*)  d_in[1];
    const float* Wqkv = (const float*)d_in[2];
    const float* Wout = (const float*)d_in[3];

    float* out = (float*)d_out;
    float* kc  = out + (size_t)BS * HID;
    float* vc  = kc  + (size_t)BS * HID;

    char*  ws    = (char*)d_ws;
    short* qb    = (short*)ws;                          // 8 MB  [BS][HID] bf16
    short* wqkvT = (short*)(ws + (8u << 20));           // 6 MB (dead after gemm1)
    short* woutT = (short*)(ws + (14u << 20));          // 2 MB
    const bool full = ws_size >= (32u << 20);
    short* kb = full ? (short*)(ws + (16u << 20)) : nullptr;  // 8 MB [BS][HID] bf16
    short* vt = full ? (short*)(ws + (24u << 20)) : nullptr;  // 8 MB [B][H][64][SEQ] bf16

    // xb (bf16 x, 8 MB) + attn partials (16 MB) live in the `out` region of
    // d_out — xb is consumed by gemm1 before attn writes partials there.
    short* xb    = (short*)out;
    short* opart = (short*)out;                 // [2][BS][HID] bf16 = 16 MB
    float* lsp   = (float*)wqkvT;               // 512 KB in dead wqkvT region

    prep<<<dim3(1280), dim3(256), 0, stream>>>(Wqkv, Wout, x, wqkvT, woutT, xb);

    gemm_lds<0,128><<<dim3(24, 32), dim3(256), 0, stream>>>(
        xb, wqkvT, nullptr, kc, vc, qb, kb, vt, BS, 3*HID, HID);

    if (full) {
        attn_kernel<true><<<dim3(2048), dim3(256), 0, stream>>>(
            qb, kb, vt, kc, vc, mask, qb, opart, lsp);
        combine<<<dim3(BS*HID/8/256), dim3(256), 0, stream>>>(opart, lsp, qb);
    } else {
        attn_kernel<false><<<dim3(1024), dim3(256), 0, stream>>>(
            qb, nullptr, nullptr, kc, vc, mask, qb, nullptr, nullptr);
    }

    gemm_lds<1,64><<<dim3(16, 32), dim3(256), 0, stream>>>(
        qb, woutT, out, nullptr, nullptr, nullptr, nullptr, nullptr, BS, HID, HID);
}

// Round 10
// 230.424 us; speedup vs baseline: 1.7873x; 1.0107x over previous
//
#include <hip/hip_runtime.h>
#include <hip/hip_bf16.h>
#include <cstdint>
#include <cstddef>

#define HID 1024
#define NH 16
#define DH 64
#define SEQ 2048
#define BATCH 2
#define BS (BATCH*SEQ)   // 4096
#define LOG2E 1.4426950408889634f
#define PADK 68          // attn LDS row stride in shorts (136B) — measured 0 conflicts

typedef __attribute__((ext_vector_type(8))) short bf16x8;
typedef __attribute__((ext_vector_type(4))) float f32x4;

static __device__ __forceinline__ float fast_exp2(float x) {
    return __builtin_amdgcn_exp2f(x);
}

// f32->bf16 RNE via the COMPILER's native path (round-5 verified).
// Hand-written v_cvt_pk asm miscompiles here (rounds 2/3) — do not use.
static __device__ __forceinline__ short f2bf(float f) {
    union { __hip_bfloat16 h; short s; } cv;
    cv.h = __float2bfloat16(f);
    return cv.s;
}
static __device__ __forceinline__ unsigned pack2(float a, float b) {
    union { __hip_bfloat162 h2; unsigned u; } cv;
    cv.h2 = __float22bfloat162_rn(make_float2(a, b));
    return cv.u;
}

// global -> LDS direct DMA, 16B per lane (global_load_lds_dwordx4).
typedef const __attribute__((address_space(1))) unsigned gas_u32;
typedef __attribute__((address_space(3))) unsigned las_u32;
static __device__ __forceinline__ void gload_lds16(const short* g, short* l) {
    __builtin_amdgcn_global_load_lds((gas_u32*)g, (las_u32*)l, 16, 0, 0);
}

// ---------------------------------------------------------------------------
// prep: Wqkv [1024][3072] fp32 -> wqkvT [3072][1024] bf16 (transpose+convert)
//       Wout [1024][1024] fp32 -> woutT [1024][1024] bf16
//       x    [4096][1024] fp32 -> xb    [4096][1024] bf16 (straight convert)
// ---------------------------------------------------------------------------
__global__ __launch_bounds__(256)
void prep(const float* __restrict__ Wqkv, const float* __restrict__ Wout,
          const float* __restrict__ x,
          short* __restrict__ wqkvT, short* __restrict__ woutT,
          short* __restrict__ xb)
{
    __shared__ short tl[64][66];
    const int bid = blockIdx.x;
    const int t = threadIdx.x;

    if (bid >= 1024) {
        const float4* x4 = (const float4*)x;
        uint2* xo = (uint2*)xb;
        const int base = (bid - 1024) * 4096 + t;
        #pragma unroll
        for (int i = 0; i < 16; ++i) {
            float4 f = x4[base + i*256];
            xo[base + i*256] = make_uint2(pack2(f.x, f.y), pack2(f.z, f.w));
        }
        return;
    }

    const float* W; short* WT; int Nw, K, k0, n0;
    if (bid < 768) {
        W = Wqkv; WT = wqkvT; Nw = 3072; K = 1024;
        n0 = (bid % 48) * 64; k0 = (bid / 48) * 64;
    } else {
        W = Wout; WT = woutT; Nw = 1024; K = 1024;
        int b2 = bid - 768;
        n0 = (b2 & 15) * 64; k0 = (b2 >> 4) * 64;
    }
    const int r = t >> 2, c0 = (t & 3) * 16;
    const float* src = W + (size_t)(k0 + r) * Nw + n0 + c0;
    #pragma unroll
    for (int i = 0; i < 16; i += 4) {
        float4 f = *(const float4*)(src + i);
        tl[r][c0+i+0] = f2bf(f.x); tl[r][c0+i+1] = f2bf(f.y);
        tl[r][c0+i+2] = f2bf(f.z); tl[r][c0+i+3] = f2bf(f.w);
    }
    __syncthreads();
    short* dst = WT + (size_t)(n0 + r) * K + k0 + c0;
    unsigned buf[8];
    #pragma unroll
    for (int i = 0; i < 8; ++i) {
        unsigned lo = (unsigned short)tl[c0 + 2*i    ][r];
        unsigned hi = (unsigned short)tl[c0 + 2*i + 1][r];
        buf[i] = lo | (hi << 16);
    }
    *(uint4*)dst       = *(uint4*)&buf[0];
    *((uint4*)dst + 1) = *(uint4*)&buf[4];
}

// ---------------------------------------------------------------------------
// vtrans: vc [BS][HID] fp32 -> vt [B][NH][DH][SEQ] bf16, via LDS 64x64 tiles
// (same proven pattern as prep's W transpose; coalesced on both sides).
// Values bit-identical to the old gemm1 vt scatter: RNE(vc) == RNE(acc).
// grid 1024: b(2) x h(16) x stile(32).
// ---------------------------------------------------------------------------
__global__ __launch_bounds__(256)
void vtrans(const float* __restrict__ vc, short* __restrict__ vt)
{
    __shared__ short tl[64][66];
    const int bid = blockIdx.x;
    const int t = threadIdx.x;
    const int st = bid & 31;            // s-tile
    const int h  = (bid >> 5) & 15;
    const int b  = bid >> 9;
    const int s0 = st * 64;

    const int r = t >> 2, c0 = (t & 3) * 16;   // r: s-row 0..63, c0: d group
    const float* src = vc + ((size_t)(b*SEQ + s0 + r)) * HID + h*DH + c0;
    #pragma unroll
    for (int i = 0; i < 16; i += 4) {
        float4 f = *(const float4*)(src + i);
        tl[r][c0+i+0] = f2bf(f.x); tl[r][c0+i+1] = f2bf(f.y);
        tl[r][c0+i+2] = f2bf(f.z); tl[r][c0+i+3] = f2bf(f.w);
    }
    __syncthreads();
    // write: row d = r, cols s0+c0..+15 (32B contiguous along s)
    short* dst = vt + ((size_t)((b*NH + h)*DH + r)) * SEQ + s0 + c0;
    unsigned buf[8];
    #pragma unroll
    for (int i = 0; i < 8; ++i) {
        unsigned lo = (unsigned short)tl[c0 + 2*i    ][r];
        unsigned hi = (unsigned short)tl[c0 + 2*i + 1][r];
        buf[i] = lo | (hi << 16);
    }
    *(uint4*)dst       = *(uint4*)&buf[0];
    *((uint4*)dst + 1) = *(uint4*)&buf[4];
}

// ---------------------------------------------------------------------------
// m97-structure bf16 MFMA GEMM: C = A @ Bt^T. 128xBN tile, BK=64.
// (vt scatter removed from epilogue — vtrans kernel produces vt instead.)
// ---------------------------------------------------------------------------
template<int CMODE, int BN>
__global__ __launch_bounds__(256, 3)
void gemm_lds(const short* __restrict__ A, const short* __restrict__ Bt,
              float* __restrict__ Cf,
              float* __restrict__ kc, float* __restrict__ vc,
              short* __restrict__ qb, short* __restrict__ kb,
              int M, int N, int K)
{
    constexpr int WN = BN / 2;      // wave N span
    constexpr int NF = WN / 16;     // N fragments per wave
    __shared__ short As[128*64];
    __shared__ short Bs[BN*64];
    const int t    = threadIdx.x;
    const int wave = t >> 6, lane = t & 63;
    const int quad = lane >> 4, l16 = lane & 15;
    const int wrow = (wave & 1) * 64, wcol = (wave >> 1) * WN;
    const int n0 = blockIdx.x * BN, m0 = blockIdx.y * 128;

    f32x4 acc[4][NF];
    #pragma unroll
    for (int mi = 0; mi < 4; ++mi)
        #pragma unroll
        for (int nj = 0; nj < NF; ++nj) acc[mi][nj] = (f32x4){0.f,0.f,0.f,0.f};

    const int lr = lane >> 3;          // row within 8-row chunk
    const int lc = (lane & 7) * 8;     // col (shorts) within row
    const short* Ab = A  + (size_t)(m0 + wave*32       + lr) * K + lc;
    const short* Bb = Bt + (size_t)(n0 + wave*(BN/4)   + lr) * K + lc;
    short* AsW = As + (wave*32)      * 64;
    short* BsW = Bs + (wave*(BN/4))  * 64;

    for (int kt = 0; kt < K; kt += 64) {
        #pragma unroll
        for (int i = 0; i < 4; ++i)
            gload_lds16(Ab + (size_t)(i*8)*K + kt, AsW + i*512);
        #pragma unroll
        for (int i = 0; i < BN/32; ++i)
            gload_lds16(Bb + (size_t)(i*8)*K + kt, BsW + i*512);
        __syncthreads();

        #pragma unroll
        for (int ks = 0; ks < 2; ++ks) {
            bf16x8 af[4], bfr[NF];
            #pragma unroll
            for (int mi = 0; mi < 4; ++mi)
                af[mi] = *(const bf16x8*)&As[(wrow + mi*16 + l16)*64 + ks*32 + quad*8];
            #pragma unroll
            for (int nj = 0; nj < NF; ++nj)
                bfr[nj] = *(const bf16x8*)&Bs[(wcol + nj*16 + l16)*64 + ks*32 + quad*8];
            #pragma unroll
            for (int mi = 0; mi < 4; ++mi)
                #pragma unroll
                for (int nj = 0; nj < NF; ++nj)
                    acc[mi][nj] = __builtin_amdgcn_mfma_f32_16x16x32_bf16(
                        af[mi], bfr[nj], acc[mi][nj], 0, 0, 0);
        }
        __syncthreads();
    }

    const int region = (CMODE == 0) ? (n0 >> 10) : 0;
    #pragma unroll
    for (int mi = 0; mi < 4; ++mi) {
        int rbase = m0 + wrow + mi*16 + quad*4;
        #pragma unroll
        for (int nj = 0; nj < NF; ++nj) {
            int col = n0 + wcol + nj*16 + l16;
            if (CMODE == 1) {
                #pragma unroll
                for (int reg = 0; reg < 4; ++reg)
                    Cf[(size_t)(rbase + reg) * N + col] = acc[mi][nj][reg];
            } else {
                int c = col & 1023;
                if (region == 0) {
                    #pragma unroll
                    for (int reg = 0; reg < 4; ++reg)
                        qb[(size_t)(rbase + reg) * HID + c] = f2bf(acc[mi][nj][reg] * LOG2E);
                } else if (region == 1) {
                    #pragma unroll
                    for (int reg = 0; reg < 4; ++reg) {
                        float v = acc[mi][nj][reg];
                        kc[(size_t)(rbase + reg) * HID + c] = v;
                        if (kb) kb[(size_t)(rbase + reg) * HID + c] = f2bf(v);
                    }
                } else {
                    #pragma unroll
                    for (int reg = 0; reg < 4; ++reg)
                        vc[(size_t)(rbase + reg) * HID + c] = acc[mi][nj][reg];
                }
            }
        }
    }
}

// ---------------------------------------------------------------------------
// Flash MFMA attention v9: R5 single-pass structure (best measured, 92.6us)
// + XCD-affinity block decode: each XCD owns 4 complete (b,h) pairs so K/V
// panels are fetched from HBM once per XCD (FETCH was 2.8x working set).
// ---------------------------------------------------------------------------
template<bool KVB>
__global__ __launch_bounds__(256, 4)
void attn_kernel(const short* qb,
                 const short* __restrict__ kb, const short* __restrict__ vtg,
                 const float* __restrict__ kc, const float* __restrict__ vc,
                 const int*   __restrict__ mask,
                 short* attn_b)   // aliases qb (same rows/cols, same WG)
{
    __shared__ short Ks[64*PADK];
    __shared__ short Vs[64*PADK];   // [d][key]
    __shared__ short Ps[64*PADK];
    __shared__ float Mk[64];        // per-key mask bias (0 or -2e9)

    const int t    = threadIdx.x;
    const int wave = t >> 6, lane = t & 63;
    const int quad = lane >> 4, l16 = lane & 15;

    // XCD-affinity decode (bijective over 1024 = 8 XCDs x 128):
    // xcd = blk&7 owns (b,h) pairs [4*xcd, 4*xcd+4); qt sweeps within XCD.
    const int blk  = blockIdx.x;
    const int xcd  = blk & 7;
    const int idx  = blk >> 3;            // 0..127
    const int pair = xcd * 4 + (idx >> 5);// 0..31
    const int qt   = idx & 31;
    const int h    = pair & 15;
    const int b    = pair >> 4;
    const int q0   = qt * 64;
    const float slope2 = exp2f(-0.5f * (float)(h + 1)) * LOG2E;
    const int* mb = mask + b * SEQ;

    const int r  = t >> 2;          // staging row 0..63
    const int c0 = (t & 3) * 16;    // staging col group

    const int qrow0 = q0 + 16*wave + quad*4;   // first q-row of this lane's regs

    // ---- Q fragments in registers (q pre-scaled by log2e) ----
    bf16x8 aq[2];
    #pragma unroll
    for (int ks = 0; ks < 2; ++ks)
        aq[ks] = *(const bf16x8*)(qb + ((size_t)(b*SEQ + q0 + 16*wave + l16)) * HID
                                     + h*DH + ks*32 + quad*8);

    float ls[4];
    f32x4 Oacc[4];
    #pragma unroll
    for (int i = 0; i < 4; ++i) {
        ls[i] = 0.f;
        Oacc[i] = (f32x4){0.f,0.f,0.f,0.f};
    }

    if (KVB) {
        // ---------------- pipelined path (bf16 kb / transposed vt) ----------
        uint4 kr0, kr1, vr0, vr1; float mval = 0.f;
        const short* kbase = kb  + ((size_t)(b*SEQ + r)) * HID + h*DH + c0;
        const short* vbase = vtg + ((size_t)((b*NH + h)*DH + r)) * SEQ + c0;

        kr0 = *(const uint4*)(kbase);
        kr1 = *(const uint4*)(kbase + 8);
        vr0 = *(const uint4*)(vbase);
        vr1 = *(const uint4*)(vbase + 8);
        if (t < 64) mval = (mb[t] == 0) ? -2.0e9f : 0.f;

        for (int kt = 0; kt < 32; ++kt) {
            const int j0 = kt * 64;
            __syncthreads();   // prev-iter LDS reads complete

            *(uint4*)&Ks[r*PADK + c0]     = kr0;
            *(uint4*)&Ks[r*PADK + c0 + 8] = kr1;
            *(uint4*)&Vs[r*PADK + c0]     = vr0;
            *(uint4*)&Vs[r*PADK + c0 + 8] = vr1;
            if (t < 64) Mk[t] = mval;

            if (kt < 31) {
                const short* kn = kbase + (size_t)(j0 + 64) * HID;
                const short* vn = vbase + (j0 + 64);
                kr0 = *(const uint4*)(kn);
                kr1 = *(const uint4*)(kn + 8);
                vr0 = *(const uint4*)(vn);
                vr1 = *(const uint4*)(vn + 8);
                if (t < 64) mval = (mb[j0 + 64 + t] == 0) ? -2.0e9f : 0.f;
            }
            __syncthreads();   // staging visible

            // ---- QK^T ----
            f32x4 S[4];
            #pragma unroll
            for (int nt = 0; nt < 4; ++nt) S[nt] = (f32x4){0.f,0.f,0.f,0.f};
            #pragma unroll
            for (int ks = 0; ks < 2; ++ks) {
                bf16x8 bk[4];
                #pragma unroll
                for (int nt = 0; nt < 4; ++nt)
                    bk[nt] = *(const bf16x8*)&Ks[(nt*16 + l16)*PADK + ks*32 + quad*8];
                __builtin_amdgcn_s_setprio(1);
                #pragma unroll
                for (int nt = 0; nt < 4; ++nt)
                    S[nt] = __builtin_amdgcn_mfma_f32_16x16x32_bf16(
                        aq[ks], bk[nt], S[nt], 0, 0, 0);
                __builtin_amdgcn_s_setprio(0);
            }

            // ---- bias + mask + unnormalized exp2, P -> LDS ----
            #pragma unroll
            for (int nt = 0; nt < 4; ++nt) {
                int j = j0 + nt*16 + l16;
                float mn  = Mk[nt*16 + l16];
                float fdb = (float)(j - qrow0);
                float p[4];
                #pragma unroll
                for (int reg = 0; reg < 4; ++reg) {
                    float d = fminf(fdb - (float)reg, 0.f);
                    p[reg] = fast_exp2(fmaf(slope2, d, S[nt][reg]) + mn);
                    ls[reg] += p[reg];
                }
                #pragma unroll
                for (int reg = 0; reg < 4; ++reg)
                    Ps[(16*wave + quad*4 + reg)*PADK + nt*16 + l16] = f2bf(p[reg]);
            }

            // ---- PV (unnormalized accumulate) ----
            #pragma unroll
            for (int ks = 0; ks < 2; ++ks) {
                bf16x8 ap = *(const bf16x8*)&Ps[(16*wave + l16)*PADK + ks*32 + quad*8];
                bf16x8 bv[4];
                #pragma unroll
                for (int nt = 0; nt < 4; ++nt)
                    bv[nt] = *(const bf16x8*)&Vs[(nt*16 + l16)*PADK + ks*32 + quad*8];
                __builtin_amdgcn_s_setprio(1);
                #pragma unroll
                for (int nt = 0; nt < 4; ++nt)
                    Oacc[nt] = __builtin_amdgcn_mfma_f32_16x16x32_bf16(
                        ap, bv[nt], Oacc[nt], 0, 0, 0);
                __builtin_amdgcn_s_setprio(0);
            }
        }
    } else {
        // ---------------- fallback: fp32 kc/vc staging ----------------------
        for (int kt = 0; kt < 32; ++kt) {
            const int j0 = kt * 64;
            __syncthreads();
            {
                const float* src = kc + ((size_t)(b*SEQ + j0 + r)) * HID + h*DH + c0;
                #pragma unroll
                for (int i = 0; i < 16; i += 4) {
                    float4 f = *(const float4*)(src + i);
                    *(unsigned*)&Ks[r*PADK + c0 + i]     = pack2(f.x, f.y);
                    *(unsigned*)&Ks[r*PADK + c0 + i + 2] = pack2(f.z, f.w);
                }
                int kp = t & 31, db = t >> 5;
                const float* v0 = vc + ((size_t)(b*SEQ + j0 + 2*kp)) * HID + h*DH + db*8;
                const float* v1 = v0 + HID;
                float4 a0 = *(const float4*)v0, a1 = *(const float4*)(v0 + 4);
                float4 b0 = *(const float4*)v1, b1 = *(const float4*)(v1 + 4);
                float va[8]  = {a0.x,a0.y,a0.z,a0.w,a1.x,a1.y,a1.z,a1.w};
                float vb2[8] = {b0.x,b0.y,b0.z,b0.w,b1.x,b1.y,b1.z,b1.w};
                #pragma unroll
                for (int i = 0; i < 8; ++i)
                    *(unsigned*)&Vs[(db*8 + i)*PADK + 2*kp] = pack2(va[i], vb2[i]);
                if (t < 64) Mk[t] = (mb[j0 + t] == 0) ? -2.0e9f : 0.f;
            }
            __syncthreads();

            f32x4 S[4];
            #pragma unroll
            for (int nt = 0; nt < 4; ++nt) S[nt] = (f32x4){0.f,0.f,0.f,0.f};
            #pragma unroll
            for (int ks = 0; ks < 2; ++ks) {
                bf16x8 bk[4];
                #pragma unroll
                for (int nt = 0; nt < 4; ++nt)
                    bk[nt] = *(const bf16x8*)&Ks[(nt*16 + l16)*PADK + ks*32 + quad*8];
                #pragma unroll
                for (int nt = 0; nt < 4; ++nt)
                    S[nt] = __builtin_amdgcn_mfma_f32_16x16x32_bf16(
                        aq[ks], bk[nt], S[nt], 0, 0, 0);
            }

            #pragma unroll
            for (int nt = 0; nt < 4; ++nt) {
                int j = j0 + nt*16 + l16;
                float mn  = Mk[nt*16 + l16];
                float fdb = (float)(j - qrow0);
                float p[4];
                #pragma unroll
                for (int reg = 0; reg < 4; ++reg) {
                    float d = fminf(fdb - (float)reg, 0.f);
                    p[reg] = fast_exp2(fmaf(slope2, d, S[nt][reg]) + mn);
                    ls[reg] += p[reg];
                }
                #pragma unroll
                for (int reg = 0; reg < 4; ++reg)
                    Ps[(16*wave + quad*4 + reg)*PADK + nt*16 + l16] = f2bf(p[reg]);
            }

            #pragma unroll
            for (int ks = 0; ks < 2; ++ks) {
                bf16x8 ap = *(const bf16x8*)&Ps[(16*wave + l16)*PADK + ks*32 + quad*8];
                bf16x8 bv[4];
                #pragma unroll
                for (int nt = 0; nt < 4; ++nt)
                    bv[nt] = *(const bf16x8*)&Vs[(nt*16 + l16)*PADK + ks*32 + quad*8];
                #pragma unroll
                for (int nt = 0; nt < 4; ++nt)
                    Oacc[nt] = __builtin_amdgcn_mfma_f32_16x16x32_bf16(
                        ap, bv[nt], Oacc[nt], 0, 0, 0);
            }
        }
    }

    // ---- single cross-lane row-sum reduction (within 16-lane group) ----
    float rinv[4];
    #pragma unroll
    for (int reg = 0; reg < 4; ++reg) {
        float s0 = ls[reg];
        #pragma unroll
        for (int off = 1; off <= 8; off <<= 1) s0 += __shfl_xor(s0, off, 64);
        rinv[reg] = 1.0f / s0;
    }

    // ---- epilogue ----
    short* ap = attn_b + (size_t)b * SEQ * HID + h * DH;
    #pragma unroll
    for (int nt = 0; nt < 4; ++nt) {
        int dcol = nt*16 + l16;
        #pragma unroll
        for (int reg = 0; reg < 4; ++reg) {
            int row = q0 + 16*wave + quad*4 + reg;
            ap[(size_t)row * HID + dcol] = f2bf(Oacc[nt][reg] * rinv[reg]);
        }
    }
}

// ---------------------------------------------------------------------------
extern "C" void kernel_launch(void* const* d_in, const int* in_sizes, int n_in,
                              void* d_out, int out_size, void* d_ws, size_t ws_size,
                              hipStream_t stream)
{
    const float* x    = (const float*)d_in[0];
    const int*   mask = (const int*)  d_in[1];
    const float* Wqkv = (const float*)d_in[2];
    const float* Wout = (const float*)d_in[3];

    float* out = (float*)d_out;
    float* kc  = out + (size_t)BS * HID;
    float* vc  = kc  + (size_t)BS * HID;

    char*  ws    = (char*)d_ws;
    short* qb    = (short*)ws;                          // 8 MB  [BS][HID] bf16
    short* wqkvT = (short*)(ws + (8u << 20));           // 6 MB
    short* woutT = (short*)(ws + (14u << 20));          // 2 MB
    const bool full = ws_size >= (32u << 20);
    short* kb = full ? (short*)(ws + (16u << 20)) : nullptr;  // 8 MB [BS][HID] bf16
    short* vt = full ? (short*)(ws + (24u << 20)) : nullptr;  // 8 MB [B][H][64][SEQ] bf16

    short* xb = (short*)out;   // bf16 x in dead region of d_out

    prep<<<dim3(1280), dim3(256), 0, stream>>>(Wqkv, Wout, x, wqkvT, woutT, xb);

    gemm_lds<0,128><<<dim3(24, 32), dim3(256), 0, stream>>>(
        xb, wqkvT, nullptr, kc, vc, qb, kb, BS, 3*HID, HID);

    if (full) {
        vtrans<<<dim3(1024), dim3(256), 0, stream>>>(vc, vt);
        attn_kernel<true><<<dim3(1024), dim3(256), 0, stream>>>(
            qb, kb, vt, kc, vc, mask, qb);
    } else {
        attn_kernel<false><<<dim3(1024), dim3(256), 0, stream>>>(
            qb, nullptr, nullptr, kc, vc, mask, qb);
    }

    gemm_lds<1,64><<<dim3(16, 32), dim3(256), 0, stream>>>(
        qb, woutT, out, nullptr, nullptr, nullptr, nullptr, BS, HID, HID);
}

// Round 11
// 228.454 us; speedup vs baseline: 1.8027x; 1.0086x over previous
//
#include <hip/hip_runtime.h>
#include <hip/hip_bf16.h>
#include <cstdint>
#include <cstddef>

#define HID 1024
#define NH 16
#define DH 64
#define SEQ 2048
#define BATCH 2
#define BS (BATCH*SEQ)   // 4096
#define LOG2E 1.4426950408889634f
#define PADK 68          // attn LDS row stride in shorts (136B) — measured 0 conflicts

typedef __attribute__((ext_vector_type(8))) short bf16x8;
typedef __attribute__((ext_vector_type(4))) float f32x4;

static __device__ __forceinline__ float fast_exp2(float x) {
    return __builtin_amdgcn_exp2f(x);
}

// f32->bf16 RNE via the COMPILER's native path (round-5 verified).
// Hand-written v_cvt_pk asm miscompiles here (rounds 2/3) — do not use.
static __device__ __forceinline__ short f2bf(float f) {
    union { __hip_bfloat16 h; short s; } cv;
    cv.h = __float2bfloat16(f);
    return cv.s;
}
static __device__ __forceinline__ unsigned pack2(float a, float b) {
    union { __hip_bfloat162 h2; unsigned u; } cv;
    cv.h2 = __float22bfloat162_rn(make_float2(a, b));
    return cv.u;
}

// global -> LDS direct DMA, 16B per lane (global_load_lds_dwordx4).
typedef const __attribute__((address_space(1))) unsigned gas_u32;
typedef __attribute__((address_space(3))) unsigned las_u32;
static __device__ __forceinline__ void gload_lds16(const short* g, short* l) {
    __builtin_amdgcn_global_load_lds((gas_u32*)g, (las_u32*)l, 16, 0, 0);
}

// ---------------------------------------------------------------------------
// prep: Wqkv [1024][3072] fp32 -> wqkvT [3072][1024] bf16 (transpose+convert)
//       Wout [1024][1024] fp32 -> woutT [1024][1024] bf16
//       x    [4096][1024] fp32 -> xb    [4096][1024] bf16 (straight convert)
// ---------------------------------------------------------------------------
__global__ __launch_bounds__(256)
void prep(const float* __restrict__ Wqkv, const float* __restrict__ Wout,
          const float* __restrict__ x,
          short* __restrict__ wqkvT, short* __restrict__ woutT,
          short* __restrict__ xb)
{
    __shared__ short tl[64][66];
    const int bid = blockIdx.x;
    const int t = threadIdx.x;

    if (bid >= 1024) {
        const float4* x4 = (const float4*)x;
        uint2* xo = (uint2*)xb;
        const int base = (bid - 1024) * 4096 + t;
        #pragma unroll
        for (int i = 0; i < 16; ++i) {
            float4 f = x4[base + i*256];
            xo[base + i*256] = make_uint2(pack2(f.x, f.y), pack2(f.z, f.w));
        }
        return;
    }

    const float* W; short* WT; int Nw, K, k0, n0;
    if (bid < 768) {
        W = Wqkv; WT = wqkvT; Nw = 3072; K = 1024;
        n0 = (bid % 48) * 64; k0 = (bid / 48) * 64;
    } else {
        W = Wout; WT = woutT; Nw = 1024; K = 1024;
        int b2 = bid - 768;
        n0 = (b2 & 15) * 64; k0 = (b2 >> 4) * 64;
    }
    const int r = t >> 2, c0 = (t & 3) * 16;
    const float* src = W + (size_t)(k0 + r) * Nw + n0 + c0;
    #pragma unroll
    for (int i = 0; i < 16; i += 4) {
        float4 f = *(const float4*)(src + i);
        tl[r][c0+i+0] = f2bf(f.x); tl[r][c0+i+1] = f2bf(f.y);
        tl[r][c0+i+2] = f2bf(f.z); tl[r][c0+i+3] = f2bf(f.w);
    }
    __syncthreads();
    short* dst = WT + (size_t)(n0 + r) * K + k0 + c0;
    unsigned buf[8];
    #pragma unroll
    for (int i = 0; i < 8; ++i) {
        unsigned lo = (unsigned short)tl[c0 + 2*i    ][r];
        unsigned hi = (unsigned short)tl[c0 + 2*i + 1][r];
        buf[i] = lo | (hi << 16);
    }
    *(uint4*)dst       = *(uint4*)&buf[0];
    *((uint4*)dst + 1) = *(uint4*)&buf[4];
}

// ---------------------------------------------------------------------------
// m97-structure bf16 MFMA GEMM: C = A @ Bt^T. 128xBN tile, BK=64.
// T1 XCD-chunked block remap: default dispatch round-robins linear blocks
// across the 8 XCD L2s, so every XCD re-fetches every A/B panel. Remap
// virt = (lin%8)*(nblk/8) + lin/8 (bijective; nblk%8==0) gives each XCD a
// contiguous m-row chunk -> A panels L2-resident per XCD.
// CMODE 0 epilogue: q -> qb bf16 (pre-scaled log2e), k -> kc fp32 + kb bf16,
// v -> vc fp32 + vt bf16 [b][h][d][s] scatter. CMODE 1: plain fp32 C.
// ---------------------------------------------------------------------------
template<int CMODE, int BN>
__global__ __launch_bounds__(256, 3)
void gemm_lds(const short* __restrict__ A, const short* __restrict__ Bt,
              float* __restrict__ Cf,
              float* __restrict__ kc, float* __restrict__ vc,
              short* __restrict__ qb, short* __restrict__ kb, short* __restrict__ vt,
              int M, int N, int K)
{
    constexpr int WN = BN / 2;      // wave N span
    constexpr int NF = WN / 16;     // N fragments per wave
    __shared__ short As[128*64];
    __shared__ short Bs[BN*64];
    const int t    = threadIdx.x;
    const int wave = t >> 6, lane = t & 63;
    const int quad = lane >> 4, l16 = lane & 15;
    const int wrow = (wave & 1) * 64, wcol = (wave >> 1) * WN;

    // T1 remap (nblk = gridDim.x * gridDim.y, divisible by 8)
    const int nx   = gridDim.x;
    const int lin  = blockIdx.y * nx + blockIdx.x;
    const int chunk = (nx * gridDim.y) >> 3;
    const int virt = (lin & 7) * chunk + (lin >> 3);
    const int n0 = (virt % nx) * BN, m0 = (virt / nx) * 128;

    f32x4 acc[4][NF];
    #pragma unroll
    for (int mi = 0; mi < 4; ++mi)
        #pragma unroll
        for (int nj = 0; nj < NF; ++nj) acc[mi][nj] = (f32x4){0.f,0.f,0.f,0.f};

    const int lr = lane >> 3;          // row within 8-row chunk
    const int lc = (lane & 7) * 8;     // col (shorts) within row
    const short* Ab = A  + (size_t)(m0 + wave*32       + lr) * K + lc;
    const short* Bb = Bt + (size_t)(n0 + wave*(BN/4)   + lr) * K + lc;
    short* AsW = As + (wave*32)      * 64;
    short* BsW = Bs + (wave*(BN/4))  * 64;

    for (int kt = 0; kt < K; kt += 64) {
        #pragma unroll
        for (int i = 0; i < 4; ++i)
            gload_lds16(Ab + (size_t)(i*8)*K + kt, AsW + i*512);
        #pragma unroll
        for (int i = 0; i < BN/32; ++i)
            gload_lds16(Bb + (size_t)(i*8)*K + kt, BsW + i*512);
        __syncthreads();

        #pragma unroll
        for (int ks = 0; ks < 2; ++ks) {
            bf16x8 af[4], bfr[NF];
            #pragma unroll
            for (int mi = 0; mi < 4; ++mi)
                af[mi] = *(const bf16x8*)&As[(wrow + mi*16 + l16)*64 + ks*32 + quad*8];
            #pragma unroll
            for (int nj = 0; nj < NF; ++nj)
                bfr[nj] = *(const bf16x8*)&Bs[(wcol + nj*16 + l16)*64 + ks*32 + quad*8];
            #pragma unroll
            for (int mi = 0; mi < 4; ++mi)
                #pragma unroll
                for (int nj = 0; nj < NF; ++nj)
                    acc[mi][nj] = __builtin_amdgcn_mfma_f32_16x16x32_bf16(
                        af[mi], bfr[nj], acc[mi][nj], 0, 0, 0);
        }
        __syncthreads();
    }

    const int region = (CMODE == 0) ? (n0 >> 10) : 0;
    #pragma unroll
    for (int mi = 0; mi < 4; ++mi) {
        int rbase = m0 + wrow + mi*16 + quad*4;
        #pragma unroll
        for (int nj = 0; nj < NF; ++nj) {
            int col = n0 + wcol + nj*16 + l16;
            if (CMODE == 1) {
                #pragma unroll
                for (int reg = 0; reg < 4; ++reg)
                    Cf[(size_t)(rbase + reg) * N + col] = acc[mi][nj][reg];
            } else {
                int c = col & 1023;
                if (region == 0) {
                    #pragma unroll
                    for (int reg = 0; reg < 4; ++reg)
                        qb[(size_t)(rbase + reg) * HID + c] = f2bf(acc[mi][nj][reg] * LOG2E);
                } else if (region == 1) {
                    #pragma unroll
                    for (int reg = 0; reg < 4; ++reg) {
                        float v = acc[mi][nj][reg];
                        kc[(size_t)(rbase + reg) * HID + c] = v;
                        if (kb) kb[(size_t)(rbase + reg) * HID + c] = f2bf(v);
                    }
                } else {
                    #pragma unroll
                    for (int reg = 0; reg < 4; ++reg)
                        vc[(size_t)(rbase + reg) * HID + c] = acc[mi][nj][reg];
                    if (vt) {
                        int b = rbase >> 11, s = rbase & 2047;
                        int h = c >> 6, d = c & 63;
                        unsigned u[2] = {pack2(acc[mi][nj][0], acc[mi][nj][1]),
                                         pack2(acc[mi][nj][2], acc[mi][nj][3])};
                        *(uint2*)&vt[((size_t)((b*16 + h)*64 + d)) * SEQ + s] = *(uint2*)u;
                    }
                }
            }
        }
    }
}

// ---------------------------------------------------------------------------
// Flash MFMA attention v9 (champion structure): R5 single-pass (QBLK=64,
// KVBLK=64, 256 thr, 26.6KB LDS, VGPR 52) + XCD-affinity decode (R10: FETCH
// 69.7 -> 12.4 MB). Attn is serial-chain-bound: VALU cuts (R5), occupancy
// x2 (R9), FETCH /5.6 (R10) were all time-neutral; dbuf (R7) and bigger
// tiles (R6) regressed. Do not perturb without a full swapped-QK rewrite.
// ---------------------------------------------------------------------------
template<bool KVB>
__global__ __launch_bounds__(256, 4)
void attn_kernel(const short* qb,
                 const short* __restrict__ kb, const short* __restrict__ vtg,
                 const float* __restrict__ kc, const float* __restrict__ vc,
                 const int*   __restrict__ mask,
                 short* attn_b)   // aliases qb (same rows/cols, same WG)
{
    __shared__ short Ks[64*PADK];
    __shared__ short Vs[64*PADK];   // [d][key]
    __shared__ short Ps[64*PADK];
    __shared__ float Mk[64];        // per-key mask bias (0 or -2e9)

    const int t    = threadIdx.x;
    const int wave = t >> 6, lane = t & 63;
    const int quad = lane >> 4, l16 = lane & 15;

    // XCD-affinity decode (bijective over 1024 = 8 XCDs x 128):
    const int blk  = blockIdx.x;
    const int xcd  = blk & 7;
    const int idx  = blk >> 3;            // 0..127
    const int pair = xcd * 4 + (idx >> 5);// 0..31
    const int qt   = idx & 31;
    const int h    = pair & 15;
    const int b    = pair >> 4;
    const int q0   = qt * 64;
    const float slope2 = exp2f(-0.5f * (float)(h + 1)) * LOG2E;
    const int* mb = mask + b * SEQ;

    const int r  = t >> 2;          // staging row 0..63
    const int c0 = (t & 3) * 16;    // staging col group

    const int qrow0 = q0 + 16*wave + quad*4;   // first q-row of this lane's regs

    // ---- Q fragments in registers (q pre-scaled by log2e) ----
    bf16x8 aq[2];
    #pragma unroll
    for (int ks = 0; ks < 2; ++ks)
        aq[ks] = *(const bf16x8*)(qb + ((size_t)(b*SEQ + q0 + 16*wave + l16)) * HID
                                     + h*DH + ks*32 + quad*8);

    float ls[4];
    f32x4 Oacc[4];
    #pragma unroll
    for (int i = 0; i < 4; ++i) {
        ls[i] = 0.f;
        Oacc[i] = (f32x4){0.f,0.f,0.f,0.f};
    }

    if (KVB) {
        // ---------------- pipelined path (bf16 kb / transposed vt) ----------
        uint4 kr0, kr1, vr0, vr1; float mval = 0.f;
        const short* kbase = kb  + ((size_t)(b*SEQ + r)) * HID + h*DH + c0;
        const short* vbase = vtg + ((size_t)((b*NH + h)*DH + r)) * SEQ + c0;

        kr0 = *(const uint4*)(kbase);
        kr1 = *(const uint4*)(kbase + 8);
        vr0 = *(const uint4*)(vbase);
        vr1 = *(const uint4*)(vbase + 8);
        if (t < 64) mval = (mb[t] == 0) ? -2.0e9f : 0.f;

        for (int kt = 0; kt < 32; ++kt) {
            const int j0 = kt * 64;
            __syncthreads();   // prev-iter LDS reads complete

            *(uint4*)&Ks[r*PADK + c0]     = kr0;
            *(uint4*)&Ks[r*PADK + c0 + 8] = kr1;
            *(uint4*)&Vs[r*PADK + c0]     = vr0;
            *(uint4*)&Vs[r*PADK + c0 + 8] = vr1;
            if (t < 64) Mk[t] = mval;

            if (kt < 31) {
                const short* kn = kbase + (size_t)(j0 + 64) * HID;
                const short* vn = vbase + (j0 + 64);
                kr0 = *(const uint4*)(kn);
                kr1 = *(const uint4*)(kn + 8);
                vr0 = *(const uint4*)(vn);
                vr1 = *(const uint4*)(vn + 8);
                if (t < 64) mval = (mb[j0 + 64 + t] == 0) ? -2.0e9f : 0.f;
            }
            __syncthreads();   // staging visible

            // ---- QK^T ----
            f32x4 S[4];
            #pragma unroll
            for (int nt = 0; nt < 4; ++nt) S[nt] = (f32x4){0.f,0.f,0.f,0.f};
            #pragma unroll
            for (int ks = 0; ks < 2; ++ks) {
                bf16x8 bk[4];
                #pragma unroll
                for (int nt = 0; nt < 4; ++nt)
                    bk[nt] = *(const bf16x8*)&Ks[(nt*16 + l16)*PADK + ks*32 + quad*8];
                __builtin_amdgcn_s_setprio(1);
                #pragma unroll
                for (int nt = 0; nt < 4; ++nt)
                    S[nt] = __builtin_amdgcn_mfma_f32_16x16x32_bf16(
                        aq[ks], bk[nt], S[nt], 0, 0, 0);
                __builtin_amdgcn_s_setprio(0);
            }

            // ---- bias + mask + unnormalized exp2, P -> LDS ----
            #pragma unroll
            for (int nt = 0; nt < 4; ++nt) {
                int j = j0 + nt*16 + l16;
                float mn  = Mk[nt*16 + l16];
                float fdb = (float)(j - qrow0);
                float p[4];
                #pragma unroll
                for (int reg = 0; reg < 4; ++reg) {
                    float d = fminf(fdb - (float)reg, 0.f);
                    p[reg] = fast_exp2(fmaf(slope2, d, S[nt][reg]) + mn);
                    ls[reg] += p[reg];
                }
                #pragma unroll
                for (int reg = 0; reg < 4; ++reg)
                    Ps[(16*wave + quad*4 + reg)*PADK + nt*16 + l16] = f2bf(p[reg]);
            }

            // ---- PV (unnormalized accumulate) ----
            #pragma unroll
            for (int ks = 0; ks < 2; ++ks) {
                bf16x8 ap = *(const bf16x8*)&Ps[(16*wave + l16)*PADK + ks*32 + quad*8];
                bf16x8 bv[4];
                #pragma unroll
                for (int nt = 0; nt < 4; ++nt)
                    bv[nt] = *(const bf16x8*)&Vs[(nt*16 + l16)*PADK + ks*32 + quad*8];
                __builtin_amdgcn_s_setprio(1);
                #pragma unroll
                for (int nt = 0; nt < 4; ++nt)
                    Oacc[nt] = __builtin_amdgcn_mfma_f32_16x16x32_bf16(
                        ap, bv[nt], Oacc[nt], 0, 0, 0);
                __builtin_amdgcn_s_setprio(0);
            }
        }
    } else {
        // ---------------- fallback: fp32 kc/vc staging ----------------------
        for (int kt = 0; kt < 32; ++kt) {
            const int j0 = kt * 64;
            __syncthreads();
            {
                const float* src = kc + ((size_t)(b*SEQ + j0 + r)) * HID + h*DH + c0;
                #pragma unroll
                for (int i = 0; i < 16; i += 4) {
                    float4 f = *(const float4*)(src + i);
                    *(unsigned*)&Ks[r*PADK + c0 + i]     = pack2(f.x, f.y);
                    *(unsigned*)&Ks[r*PADK + c0 + i + 2] = pack2(f.z, f.w);
                }
                int kp = t & 31, db = t >> 5;
                const float* v0 = vc + ((size_t)(b*SEQ + j0 + 2*kp)) * HID + h*DH + db*8;
                const float* v1 = v0 + HID;
                float4 a0 = *(const float4*)v0, a1 = *(const float4*)(v0 + 4);
                float4 b0 = *(const float4*)v1, b1 = *(const float4*)(v1 + 4);
                float va[8]  = {a0.x,a0.y,a0.z,a0.w,a1.x,a1.y,a1.z,a1.w};
                float vb2[8] = {b0.x,b0.y,b0.z,b0.w,b1.x,b1.y,b1.z,b1.w};
                #pragma unroll
                for (int i = 0; i < 8; ++i)
                    *(unsigned*)&Vs[(db*8 + i)*PADK + 2*kp] = pack2(va[i], vb2[i]);
                if (t < 64) Mk[t] = (mb[j0 + t] == 0) ? -2.0e9f : 0.f;
            }
            __syncthreads();

            f32x4 S[4];
            #pragma unroll
            for (int nt = 0; nt < 4; ++nt) S[nt] = (f32x4){0.f,0.f,0.f,0.f};
            #pragma unroll
            for (int ks = 0; ks < 2; ++ks) {
                bf16x8 bk[4];
                #pragma unroll
                for (int nt = 0; nt < 4; ++nt)
                    bk[nt] = *(const bf16x8*)&Ks[(nt*16 + l16)*PADK + ks*32 + quad*8];
                #pragma unroll
                for (int nt = 0; nt < 4; ++nt)
                    S[nt] = __builtin_amdgcn_mfma_f32_16x16x32_bf16(
                        aq[ks], bk[nt], S[nt], 0, 0, 0);
            }

            #pragma unroll
            for (int nt = 0; nt < 4; ++nt) {
                int j = j0 + nt*16 + l16;
                float mn  = Mk[nt*16 + l16];
                float fdb = (float)(j - qrow0);
                float p[4];
                #pragma unroll
                for (int reg = 0; reg < 4; ++reg) {
                    float d = fminf(fdb - (float)reg, 0.f);
                    p[reg] = fast_exp2(fmaf(slope2, d, S[nt][reg]) + mn);
                    ls[reg] += p[reg];
                }
                #pragma unroll
                for (int reg = 0; reg < 4; ++reg)
                    Ps[(16*wave + quad*4 + reg)*PADK + nt*16 + l16] = f2bf(p[reg]);
            }

            #pragma unroll
            for (int ks = 0; ks < 2; ++ks) {
                bf16x8 ap = *(const bf16x8*)&Ps[(16*wave + l16)*PADK + ks*32 + quad*8];
                bf16x8 bv[4];
                #pragma unroll
                for (int nt = 0; nt < 4; ++nt)
                    bv[nt] = *(const bf16x8*)&Vs[(nt*16 + l16)*PADK + ks*32 + quad*8];
                #pragma unroll
                for (int nt = 0; nt < 4; ++nt)
                    Oacc[nt] = __builtin_amdgcn_mfma_f32_16x16x32_bf16(
                        ap, bv[nt], Oacc[nt], 0, 0, 0);
            }
        }
    }

    // ---- single cross-lane row-sum reduction (within 16-lane group) ----
    float rinv[4];
    #pragma unroll
    for (int reg = 0; reg < 4; ++reg) {
        float s0 = ls[reg];
        #pragma unroll
        for (int off = 1; off <= 8; off <<= 1) s0 += __shfl_xor(s0, off, 64);
        rinv[reg] = 1.0f / s0;
    }

    // ---- epilogue ----
    short* ap = attn_b + (size_t)b * SEQ * HID + h * DH;
    #pragma unroll
    for (int nt = 0; nt < 4; ++nt) {
        int dcol = nt*16 + l16;
        #pragma unroll
        for (int reg = 0; reg < 4; ++reg) {
            int row = q0 + 16*wave + quad*4 + reg;
            ap[(size_t)row * HID + dcol] = f2bf(Oacc[nt][reg] * rinv[reg]);
        }
    }
}

// ---------------------------------------------------------------------------
extern "C" void kernel_launch(void* const* d_in, const int* in_sizes, int n_in,
                              void* d_out, int out_size, void* d_ws, size_t ws_size,
                              hipStream_t stream)
{
    const float* x    = (const float*)d_in[0];
    const int*   mask = (const int*)  d_in[1];
    const float* Wqkv = (const float*)d_in[2];
    const float* Wout = (const float*)d_in[3];

    float* out = (float*)d_out;
    float* kc  = out + (size_t)BS * HID;
    float* vc  = kc  + (size_t)BS * HID;

    char*  ws    = (char*)d_ws;
    short* qb    = (short*)ws;                          // 8 MB  [BS][HID] bf16
    short* wqkvT = (short*)(ws + (8u << 20));           // 6 MB
    short* woutT = (short*)(ws + (14u << 20));          // 2 MB
    const bool full = ws_size >= (32u << 20);
    short* kb = full ? (short*)(ws + (16u << 20)) : nullptr;  // 8 MB [BS][HID] bf16
    short* vt = full ? (short*)(ws + (24u << 20)) : nullptr;  // 8 MB [B][H][64][SEQ] bf16

    short* xb = (short*)out;   // bf16 x in dead region of d_out

    prep<<<dim3(1280), dim3(256), 0, stream>>>(Wqkv, Wout, x, wqkvT, woutT, xb);

    gemm_lds<0,128><<<dim3(24, 32), dim3(256), 0, stream>>>(
        xb, wqkvT, nullptr, kc, vc, qb, kb, vt, BS, 3*HID, HID);

    if (full)
        attn_kernel<true><<<dim3(1024), dim3(256), 0, stream>>>(
            qb, kb, vt, kc, vc, mask, qb);
    else
        attn_kernel<false><<<dim3(1024), dim3(256), 0, stream>>>(
            qb, nullptr, nullptr, kc, vc, mask, qb);

    gemm_lds<1,64><<<dim3(16, 32), dim3(256), 0, stream>>>(
        qb, woutT, out, nullptr, nullptr, nullptr, nullptr, nullptr, BS, HID, HID);
}

// Round 14
// 225.015 us; speedup vs baseline: 1.8303x; 1.0153x over previous
//
#include <hip/hip_runtime.h>
#include <hip/hip_bf16.h>
#include <cstdint>
#include <cstddef>

#define HID 1024
#define NH 16
#define DH 64
#define SEQ 2048
#define BATCH 2
#define BS (BATCH*SEQ)   // 4096
#define LOG2E 1.4426950408889634f
#define PAD 68           // attn LDS row stride in shorts (136B) — measured 0 conflicts

typedef __attribute__((ext_vector_type(8))) short bf16x8;
typedef __attribute__((ext_vector_type(4))) float f32x4;

static __device__ __forceinline__ float fast_exp2(float x) {
    return __builtin_amdgcn_exp2f(x);
}

// f32->bf16 RNE via the COMPILER's native path (round-5 verified: passes,
// VALUBusy -3pts). Hand-written v_cvt_pk asm miscompiles here (rounds 2/3).
static __device__ __forceinline__ short f2bf(float f) {
    union { __hip_bfloat16 h; short s; } cv;
    cv.h = __float2bfloat16(f);
    return cv.s;
}
static __device__ __forceinline__ unsigned pack2(float a, float b) {
    union { __hip_bfloat162 h2; unsigned u; } cv;
    cv.h2 = __float22bfloat162_rn(make_float2(a, b));
    return cv.u;
}

// global -> LDS direct DMA, 16B per lane (global_load_lds_dwordx4).
// LDS dest is wave-uniform base + lane*16; global src is per-lane.
typedef const __attribute__((address_space(1))) unsigned gas_u32;
typedef __attribute__((address_space(3))) unsigned las_u32;
static __device__ __forceinline__ void gload_lds16(const short* g, short* l) {
    __builtin_amdgcn_global_load_lds((gas_u32*)g, (las_u32*)l, 16, 0, 0);
}

// ---------------------------------------------------------------------------
// prep: Wqkv [1024][3072] fp32 -> wqkvT [3072][1024] bf16 (transpose+convert)
//       Wout [1024][1024] fp32 -> woutT [1024][1024] bf16
//       x    [4096][1024] fp32 -> xb    [4096][1024] bf16 (straight convert)
// ---------------------------------------------------------------------------
__global__ __launch_bounds__(256)
void prep(const float* __restrict__ Wqkv, const float* __restrict__ Wout,
          const float* __restrict__ x,
          short* __restrict__ wqkvT, short* __restrict__ woutT,
          short* __restrict__ xb)
{
    __shared__ short tl[64][66];
    const int bid = blockIdx.x;
    const int t = threadIdx.x;

    if (bid >= 1024) {
        // x convert: 256 blocks x 256 threads x 16 float4 = 4M floats
        const float4* x4 = (const float4*)x;
        uint2* xo = (uint2*)xb;
        const int base = (bid - 1024) * 4096 + t;
        #pragma unroll
        for (int i = 0; i < 16; ++i) {
            float4 f = x4[base + i*256];
            xo[base + i*256] = make_uint2(pack2(f.x, f.y), pack2(f.z, f.w));
        }
        return;
    }

    const float* W; short* WT; int Nw, K, k0, n0;
    if (bid < 768) {
        W = Wqkv; WT = wqkvT; Nw = 3072; K = 1024;
        n0 = (bid % 48) * 64; k0 = (bid / 48) * 64;
    } else {
        W = Wout; WT = woutT; Nw = 1024; K = 1024;
        int b2 = bid - 768;
        n0 = (b2 & 15) * 64; k0 = (b2 >> 4) * 64;
    }
    const int r = t >> 2, c0 = (t & 3) * 16;
    const float* src = W + (size_t)(k0 + r) * Nw + n0 + c0;
    #pragma unroll
    for (int i = 0; i < 16; i += 4) {
        float4 f = *(const float4*)(src + i);
        tl[r][c0+i+0] = f2bf(f.x); tl[r][c0+i+1] = f2bf(f.y);
        tl[r][c0+i+2] = f2bf(f.z); tl[r][c0+i+3] = f2bf(f.w);
    }
    __syncthreads();
    short* dst = WT + (size_t)(n0 + r) * K + k0 + c0;
    unsigned buf[8];
    #pragma unroll
    for (int i = 0; i < 8; ++i) {
        unsigned lo = (unsigned short)tl[c0 + 2*i    ][r];
        unsigned hi = (unsigned short)tl[c0 + 2*i + 1][r];
        buf[i] = lo | (hi << 16);
    }
    *(uint4*)dst       = *(uint4*)&buf[0];
    *((uint4*)dst + 1) = *(uint4*)&buf[4];
}

// ---------------------------------------------------------------------------
// m97-structure bf16 MFMA GEMM: C = A @ Bt^T. 128xBN tile, BK=64.
// Staging via global_load_lds width=16, linear (unpadded) LDS, 2 barriers/K-step.
// CMODE 0 epilogue: q -> qb bf16 PRE-SCALED by log2e,
//                   k -> kc fp32 (+kb bf16), v -> vc fp32 (+vt bf16 [b][h][d][s])
// CMODE 1: plain fp32 C store.
// ---------------------------------------------------------------------------
template<int CMODE, int BN>
__global__ __launch_bounds__(256, 3)
void gemm_lds(const short* __restrict__ A, const short* __restrict__ Bt,
              float* __restrict__ Cf,
              float* __restrict__ kc, float* __restrict__ vc,
              short* __restrict__ qb, short* __restrict__ kb, short* __restrict__ vt,
              int M, int N, int K)
{
    constexpr int WN = BN / 2;      // wave N span
    constexpr int NF = WN / 16;     // N fragments per wave
    __shared__ short As[128*64];
    __shared__ short Bs[BN*64];
    const int t    = threadIdx.x;
    const int wave = t >> 6, lane = t & 63;
    const int quad = lane >> 4, l16 = lane & 15;
    const int wrow = (wave & 1) * 64, wcol = (wave >> 1) * WN;
    const int n0 = blockIdx.x * BN, m0 = blockIdx.y * 128;

    f32x4 acc[4][NF];
    #pragma unroll
    for (int mi = 0; mi < 4; ++mi)
        #pragma unroll
        for (int nj = 0; nj < NF; ++nj) acc[mi][nj] = (f32x4){0.f,0.f,0.f,0.f};

    // per-instruction: 64 lanes x 16B = 8 rows of 64 bf16 (128B/row), LDS linear
    const int lr = lane >> 3;          // row within 8-row chunk
    const int lc = (lane & 7) * 8;     // col (shorts) within row
    const short* Ab = A  + (size_t)(m0 + wave*32       + lr) * K + lc;
    const short* Bb = Bt + (size_t)(n0 + wave*(BN/4)   + lr) * K + lc;
    short* AsW = As + (wave*32)      * 64;
    short* BsW = Bs + (wave*(BN/4))  * 64;

    for (int kt = 0; kt < K; kt += 64) {
        #pragma unroll
        for (int i = 0; i < 4; ++i)
            gload_lds16(Ab + (size_t)(i*8)*K + kt, AsW + i*512);
        #pragma unroll
        for (int i = 0; i < BN/32; ++i)
            gload_lds16(Bb + (size_t)(i*8)*K + kt, BsW + i*512);
        __syncthreads();   // drains vmcnt, staging visible

        #pragma unroll
        for (int ks = 0; ks < 2; ++ks) {
            bf16x8 af[4], bfr[NF];
            #pragma unroll
            for (int mi = 0; mi < 4; ++mi)
                af[mi] = *(const bf16x8*)&As[(wrow + mi*16 + l16)*64 + ks*32 + quad*8];
            #pragma unroll
            for (int nj = 0; nj < NF; ++nj)
                bfr[nj] = *(const bf16x8*)&Bs[(wcol + nj*16 + l16)*64 + ks*32 + quad*8];
            #pragma unroll
            for (int mi = 0; mi < 4; ++mi)
                #pragma unroll
                for (int nj = 0; nj < NF; ++nj)
                    acc[mi][nj] = __builtin_amdgcn_mfma_f32_16x16x32_bf16(
                        af[mi], bfr[nj], acc[mi][nj], 0, 0, 0);
        }
        __syncthreads();   // LDS reads done before next-iter overwrite
    }

    const int region = (CMODE == 0) ? (n0 >> 10) : 0;
    #pragma unroll
    for (int mi = 0; mi < 4; ++mi) {
        int rbase = m0 + wrow + mi*16 + quad*4;
        #pragma unroll
        for (int nj = 0; nj < NF; ++nj) {
            int col = n0 + wcol + nj*16 + l16;
            if (CMODE == 1) {
                #pragma unroll
                for (int reg = 0; reg < 4; ++reg)
                    Cf[(size_t)(rbase + reg) * N + col] = acc[mi][nj][reg];
            } else {
                int c = col & 1023;
                if (region == 0) {
                    #pragma unroll
                    for (int reg = 0; reg < 4; ++reg)
                        qb[(size_t)(rbase + reg) * HID + c] = f2bf(acc[mi][nj][reg] * LOG2E);
                } else if (region == 1) {
                    #pragma unroll
                    for (int reg = 0; reg < 4; ++reg) {
                        float v = acc[mi][nj][reg];
                        kc[(size_t)(rbase + reg) * HID + c] = v;
                        if (kb) kb[(size_t)(rbase + reg) * HID + c] = f2bf(v);
                    }
                } else {
                    #pragma unroll
                    for (int reg = 0; reg < 4; ++reg)
                        vc[(size_t)(rbase + reg) * HID + c] = acc[mi][nj][reg];
                    if (vt) {
                        int b = rbase >> 11, s = rbase & 2047;
                        int h = c >> 6, d = c & 63;
                        unsigned u[2] = {pack2(acc[mi][nj][0], acc[mi][nj][1]),
                                         pack2(acc[mi][nj][2], acc[mi][nj][3])};
                        *(uint2*)&vt[((size_t)((b*16 + h)*64 + d)) * SEQ + s] = *(uint2*)u;
                    }
                }
            }
        }
    }
}

// ---------------------------------------------------------------------------
// Flash MFMA attention v5c (CHAMPION — R5, 225.2us total, attn 92.6us):
// UNNORMALIZED softmax (no online max), register prefetch staging, PAD=68
// conflict-free LDS, s_setprio around MFMA clusters, float-domain ALiBi,
// compiler-native bf16 converts. Session ledger: attn is serial-chain-bound
// (VALU -30% R5, occupancy x2 R9, FETCH /5.6 R10 all time-neutral; dbuf R7,
// 128-tiles R6, launch-bounds caps R8, 512-thr R12/13 all regressed/failed).
// Do not perturb.
// ---------------------------------------------------------------------------
template<bool KVB>
__global__ __launch_bounds__(256, 4)
void attn_kernel(const short* qb,
                 const short* __restrict__ kb, const short* __restrict__ vtg,
                 const float* __restrict__ kc, const float* __restrict__ vc,
                 const int*   __restrict__ mask,
                 short* attn_b)   // aliases qb (same rows/cols, same WG)
{
    __shared__ short Ks[64*PAD];
    __shared__ short Vs[64*PAD];    // [d][key]
    __shared__ short Ps[64*PAD];
    __shared__ float Mk[64];        // per-key mask bias (0 or -2e9)

    const int t    = threadIdx.x;
    const int wave = t >> 6, lane = t & 63;
    const int quad = lane >> 4, l16 = lane & 15;

    const int blk = blockIdx.x;
    const int qt  = blk & 31;
    const int h   = (blk >> 5) & 15;
    const int b   = blk >> 9;
    const int q0  = qt * 64;
    const float slope2 = exp2f(-0.5f * (float)(h + 1)) * LOG2E;
    const int* mb = mask + b * SEQ;

    const int r  = t >> 2;          // staging row 0..63
    const int c0 = (t & 3) * 16;    // staging col group

    const int qrow0 = q0 + 16*wave + quad*4;   // first q-row of this lane's regs

    // ---- Q fragments in registers (q pre-scaled by log2e) ----
    bf16x8 aq[2];
    #pragma unroll
    for (int ks = 0; ks < 2; ++ks)
        aq[ks] = *(const bf16x8*)(qb + ((size_t)(b*SEQ + q0 + 16*wave + l16)) * HID
                                     + h*DH + ks*32 + quad*8);

    float ls[4];                    // per-lane partial row sums (unnormalized)
    f32x4 Oacc[4];
    #pragma unroll
    for (int i = 0; i < 4; ++i) {
        ls[i] = 0.f;
        Oacc[i] = (f32x4){0.f,0.f,0.f,0.f};
    }

    if (KVB) {
        // ---------------- pipelined path (bf16 kb / transposed vt) ----------
        uint4 kr0, kr1, vr0, vr1; float mval = 0.f;
        const short* kbase = kb  + ((size_t)(b*SEQ + r)) * HID + h*DH + c0;
        const short* vbase = vtg + ((size_t)((b*NH + h)*DH + r)) * SEQ + c0;

        kr0 = *(const uint4*)(kbase);
        kr1 = *(const uint4*)(kbase + 8);
        vr0 = *(const uint4*)(vbase);
        vr1 = *(const uint4*)(vbase + 8);
        if (t < 64) mval = (mb[t] == 0) ? -2.0e9f : 0.f;

        for (int kt = 0; kt < 32; ++kt) {
            const int j0 = kt * 64;
            __syncthreads();   // prev-iter LDS reads complete

            *(uint4*)&Ks[r*PAD + c0]     = kr0;
            *(uint4*)&Ks[r*PAD + c0 + 8] = kr1;
            *(uint4*)&Vs[r*PAD + c0]     = vr0;
            *(uint4*)&Vs[r*PAD + c0 + 8] = vr1;
            if (t < 64) Mk[t] = mval;

            if (kt < 31) {
                const short* kn = kbase + (size_t)(j0 + 64) * HID;
                const short* vn = vbase + (j0 + 64);
                kr0 = *(const uint4*)(kn);
                kr1 = *(const uint4*)(kn + 8);
                vr0 = *(const uint4*)(vn);
                vr1 = *(const uint4*)(vn + 8);
                if (t < 64) mval = (mb[j0 + 64 + t] == 0) ? -2.0e9f : 0.f;
            }
            __syncthreads();   // staging visible

            // ---- QK^T ----
            f32x4 S[4];
            #pragma unroll
            for (int nt = 0; nt < 4; ++nt) S[nt] = (f32x4){0.f,0.f,0.f,0.f};
            #pragma unroll
            for (int ks = 0; ks < 2; ++ks) {
                bf16x8 bk[4];
                #pragma unroll
                for (int nt = 0; nt < 4; ++nt)
                    bk[nt] = *(const bf16x8*)&Ks[(nt*16 + l16)*PAD + ks*32 + quad*8];
                __builtin_amdgcn_s_setprio(1);
                #pragma unroll
                for (int nt = 0; nt < 4; ++nt)
                    S[nt] = __builtin_amdgcn_mfma_f32_16x16x32_bf16(
                        aq[ks], bk[nt], S[nt], 0, 0, 0);
                __builtin_amdgcn_s_setprio(0);
            }

            // ---- bias + mask + unnormalized exp2, P -> LDS ----
            #pragma unroll
            for (int nt = 0; nt < 4; ++nt) {
                int j = j0 + nt*16 + l16;
                float mn  = Mk[nt*16 + l16];
                float fdb = (float)(j - qrow0);   // ALiBi distance for reg 0
                float p[4];
                #pragma unroll
                for (int reg = 0; reg < 4; ++reg) {
                    float d = fminf(fdb - (float)reg, 0.f);
                    p[reg] = fast_exp2(fmaf(slope2, d, S[nt][reg]) + mn);
                    ls[reg] += p[reg];
                }
                #pragma unroll
                for (int reg = 0; reg < 4; ++reg)
                    Ps[(16*wave + quad*4 + reg)*PAD + nt*16 + l16] = f2bf(p[reg]);
            }

            // ---- PV (unnormalized accumulate) ----
            #pragma unroll
            for (int ks = 0; ks < 2; ++ks) {
                bf16x8 ap = *(const bf16x8*)&Ps[(16*wave + l16)*PAD + ks*32 + quad*8];
                bf16x8 bv[4];
                #pragma unroll
                for (int nt = 0; nt < 4; ++nt)
                    bv[nt] = *(const bf16x8*)&Vs[(nt*16 + l16)*PAD + ks*32 + quad*8];
                __builtin_amdgcn_s_setprio(1);
                #pragma unroll
                for (int nt = 0; nt < 4; ++nt)
                    Oacc[nt] = __builtin_amdgcn_mfma_f32_16x16x32_bf16(
                        ap, bv[nt], Oacc[nt], 0, 0, 0);
                __builtin_amdgcn_s_setprio(0);
            }
        }
    } else {
        // ---------------- fallback: fp32 kc/vc staging ----------------------
        for (int kt = 0; kt < 32; ++kt) {
            const int j0 = kt * 64;
            __syncthreads();
            {
                const float* src = kc + ((size_t)(b*SEQ + j0 + r)) * HID + h*DH + c0;
                #pragma unroll
                for (int i = 0; i < 16; i += 4) {
                    float4 f = *(const float4*)(src + i);
                    *(unsigned*)&Ks[r*PAD + c0 + i]     = pack2(f.x, f.y);
                    *(unsigned*)&Ks[r*PAD + c0 + i + 2] = pack2(f.z, f.w);
                }
                int kp = t & 31, db = t >> 5;
                const float* v0 = vc + ((size_t)(b*SEQ + j0 + 2*kp)) * HID + h*DH + db*8;
                const float* v1 = v0 + HID;
                float4 a0 = *(const float4*)v0, a1 = *(const float4*)(v0 + 4);
                float4 b0 = *(const float4*)v1, b1 = *(const float4*)(v1 + 4);
                float va[8]  = {a0.x,a0.y,a0.z,a0.w,a1.x,a1.y,a1.z,a1.w};
                float vb2[8] = {b0.x,b0.y,b0.z,b0.w,b1.x,b1.y,b1.z,b1.w};
                #pragma unroll
                for (int i = 0; i < 8; ++i)
                    *(unsigned*)&Vs[(db*8 + i)*PAD + 2*kp] = pack2(va[i], vb2[i]);
                if (t < 64) Mk[t] = (mb[j0 + t] == 0) ? -2.0e9f : 0.f;
            }
            __syncthreads();

            f32x4 S[4];
            #pragma unroll
            for (int nt = 0; nt < 4; ++nt) S[nt] = (f32x4){0.f,0.f,0.f,0.f};
            #pragma unroll
            for (int ks = 0; ks < 2; ++ks) {
                bf16x8 bk[4];
                #pragma unroll
                for (int nt = 0; nt < 4; ++nt)
                    bk[nt] = *(const bf16x8*)&Ks[(nt*16 + l16)*PAD + ks*32 + quad*8];
                __builtin_amdgcn_s_setprio(1);
                #pragma unroll
                for (int nt = 0; nt < 4; ++nt)
                    S[nt] = __builtin_amdgcn_mfma_f32_16x16x32_bf16(
                        aq[ks], bk[nt], S[nt], 0, 0, 0);
                __builtin_amdgcn_s_setprio(0);
            }

            #pragma unroll
            for (int nt = 0; nt < 4; ++nt) {
                int j = j0 + nt*16 + l16;
                float mn  = Mk[nt*16 + l16];
                float fdb = (float)(j - qrow0);
                float p[4];
                #pragma unroll
                for (int reg = 0; reg < 4; ++reg) {
                    float d = fminf(fdb - (float)reg, 0.f);
                    p[reg] = fast_exp2(fmaf(slope2, d, S[nt][reg]) + mn);
                    ls[reg] += p[reg];
                }
                #pragma unroll
                for (int reg = 0; reg < 4; ++reg)
                    Ps[(16*wave + quad*4 + reg)*PAD + nt*16 + l16] = f2bf(p[reg]);
            }

            #pragma unroll
            for (int ks = 0; ks < 2; ++ks) {
                bf16x8 ap = *(const bf16x8*)&Ps[(16*wave + l16)*PAD + ks*32 + quad*8];
                bf16x8 bv[4];
                #pragma unroll
                for (int nt = 0; nt < 4; ++nt)
                    bv[nt] = *(const bf16x8*)&Vs[(nt*16 + l16)*PAD + ks*32 + quad*8];
                __builtin_amdgcn_s_setprio(1);
                #pragma unroll
                for (int nt = 0; nt < 4; ++nt)
                    Oacc[nt] = __builtin_amdgcn_mfma_f32_16x16x32_bf16(
                        ap, bv[nt], Oacc[nt], 0, 0, 0);
                __builtin_amdgcn_s_setprio(0);
            }
        }
    }

    // ---- single cross-lane row-sum reduction (within 16-lane group) ----
    float rinv[4];
    #pragma unroll
    for (int reg = 0; reg < 4; ++reg) {
        float s0 = ls[reg];
        #pragma unroll
        for (int off = 1; off <= 8; off <<= 1) s0 += __shfl_xor(s0, off, 64);
        rinv[reg] = 1.0f / s0;
    }

    // ---- epilogue ----
    short* ap = attn_b + (size_t)b * SEQ * HID + h * DH;
    #pragma unroll
    for (int nt = 0; nt < 4; ++nt) {
        int dcol = nt*16 + l16;
        #pragma unroll
        for (int reg = 0; reg < 4; ++reg) {
            int row = q0 + 16*wave + quad*4 + reg;
            ap[(size_t)row * HID + dcol] = f2bf(Oacc[nt][reg] * rinv[reg]);
        }
    }
}

// ---------------------------------------------------------------------------
extern "C" void kernel_launch(void* const* d_in, const int* in_sizes, int n_in,
                              void* d_out, int out_size, void* d_ws, size_t ws_size,
                              hipStream_t stream)
{
    const float* x    = (const float*)d_in[0];
    const int*   mask = (const int*)  d_in[1];
    const float* Wqkv = (const float*)d_in[2];
    const float* Wout = (const float*)d_in[3];

    float* out = (float*)d_out;
    float* kc  = out + (size_t)BS * HID;
    float* vc  = kc  + (size_t)BS * HID;

    char*  ws    = (char*)d_ws;
    short* qb    = (short*)ws;                          // 8 MB  [BS][HID] bf16 (q*log2e, then attn)
    short* wqkvT = (short*)(ws + (8u << 20));           // 6 MB
    short* woutT = (short*)(ws + (14u << 20));           // 2 MB
    const bool full = ws_size >= (32u << 20);
    short* kb = full ? (short*)(ws + (16u << 20)) : nullptr;  // 8 MB [BS][HID] bf16
    short* vt = full ? (short*)(ws + (24u << 20)) : nullptr;  // 8 MB [B][H][64][SEQ] bf16

    // xb (bf16 x, 8 MB) lives in the `out` region of d_out (16 MB) — dead
    // until the final out-proj GEMM writes it, so no aliasing hazard.
    short* xb = (short*)out;

    prep<<<dim3(1280), dim3(256), 0, stream>>>(Wqkv, Wout, x, wqkvT, woutT, xb);

    gemm_lds<0,128><<<dim3(24, 32), dim3(256), 0, stream>>>(
        xb, wqkvT, nullptr, kc, vc, qb, kb, vt, BS, 3*HID, HID);

    if (full)
        attn_kernel<true><<<dim3(1024), dim3(256), 0, stream>>>(
            qb, kb, vt, kc, vc, mask, qb);
    else
        attn_kernel<false><<<dim3(1024), dim3(256), 0, stream>>>(
            qb, nullptr, nullptr, kc, vc, mask, qb);

    gemm_lds<1,64><<<dim3(16, 32), dim3(256), 0, stream>>>(
        qb, woutT, out, nullptr, nullptr, nullptr, nullptr, nullptr, BS, HID, HID);
}